// Round 1
// baseline (65084.271 us; speedup 1.0000x reference)
//
#include <hip/hip_runtime.h>
#include <hip/hip_bf16.h>

// 2-layer LSTM, B=32 T=512 F=1024, fp32.
// Persistent kernel: 256 WGs x 256 thr, 1 WG/CU. Each WG owns 4 features x 4 gates
// = 16 columns of [Wi;Wh] (2048x16 fp32 = 128KB, LDS-resident, XOR-swizzled).
// Per step: z = [x_t ; h] @ Wslice  (U read from global/L2, W from LDS),
// in-wave K-split-32 butterfly reduce, gates on 128 threads (c-state in regs),
// custom grid barrier (1/step). Layer-1 input = d_out (y0), overwritten in place
// with a 1-step-delayed y1 register write.

#define NB 32
#define NTT 512
#define NF 1024
#define NG 4096
#define TFE (NTT * NF)   // 524288 floats per batch row of x/out
#define BFE (NB * NF)    // 32768 floats per h phase
#define NWG 256
#define NTHR 256
#define LDS_FLOATS (32768 + 512)
#define LDS_BYTES (LDS_FLOATS * 4)

__device__ __forceinline__ float sigm(float v) { return 1.0f / (1.0f + __expf(-v)); }
__device__ __forceinline__ float tanh_s(float v) {
  float a = fabsf(v);
  float e = __expf(-2.0f * a);
  float t = (1.0f - e) / (1.0f + e);
  return v < 0.0f ? -t : t;
}

// One 8-chunk half of the per-step GEMM. ub already offset to (row w*8, col kb*4).
// W LDS layout: [k4][slot][kk] floats, slot = c ^ (k4&15)  (16B-slot XOR swizzle).
__device__ __forceinline__ void mm_part(const float* __restrict__ ub, size_t rstride,
                                        int k4base, int kb, int cq,
                                        const float* __restrict__ Wlds, float acc[8][8]) {
#pragma unroll 4
  for (int ci = 0; ci < 8; ++ci) {
    const int k4 = k4base + ci * 32 + kb;
    float4 u[8];
#pragma unroll
    for (int bi = 0; bi < 8; ++bi)
      u[bi] = *(const float4*)(ub + (size_t)bi * rstride + ci * 128);
    float4 wv[8];
    const int swz = k4 & 15;
#pragma unroll
    for (int j = 0; j < 8; ++j) {
      const int c = cq * 8 + j;
      wv[j] = *(const float4*)(Wlds + (size_t)k4 * 64 + (size_t)((c ^ swz) * 4));
    }
#pragma unroll
    for (int bi = 0; bi < 8; ++bi) {
#pragma unroll
      for (int j = 0; j < 8; ++j) {
        acc[bi][j] = fmaf(u[bi].x, wv[j].x, acc[bi][j]);
        acc[bi][j] = fmaf(u[bi].y, wv[j].y, acc[bi][j]);
        acc[bi][j] = fmaf(u[bi].z, wv[j].z, acc[bi][j]);
        acc[bi][j] = fmaf(u[bi].w, wv[j].w, acc[bi][j]);
      }
    }
  }
}

__global__ __launch_bounds__(NTHR, 1) void lstm_persist(
    const float* __restrict__ x,
    const float* __restrict__ Wi0, const float* __restrict__ Wh0, const float* __restrict__ bv0,
    const float* __restrict__ Wi1, const float* __restrict__ Wh1, const float* __restrict__ bv1,
    float* __restrict__ out, float* __restrict__ hbuf, unsigned* __restrict__ bar) {
  extern __shared__ float lds[];
  float* Wlds = lds;           // [512][16][4] swizzled = 32768 floats (128KB)
  float* zbuf = lds + 32768;   // [32][16]
  const int wg = blockIdx.x;
  const int tid = threadIdx.x;
  const int w = tid >> 6;          // wave id -> batch octet
  const int lane = tid & 63;
  const int cq = lane >> 5;        // column half (0: gates i,f ; 1: gates g,o)
  const int kb = lane & 31;        // K-split slot within wave
  unsigned gen = 0;

  auto gridbar = [&]() {
    __threadfence();
    __syncthreads();
    ++gen;
    if (tid == 0) {
      atomicAdd(bar, 1u);
      const unsigned target = (unsigned)NWG * gen;
      while (__hip_atomic_load(bar, __ATOMIC_RELAXED, __HIP_MEMORY_SCOPE_AGENT) < target)
        __builtin_amdgcn_s_sleep(2);
    }
    __syncthreads();
    __threadfence();
  };

  for (int layer = 0; layer < 2; ++layer) {
    const float* Wi = layer ? Wi1 : Wi0;
    const float* Wh = layer ? Wh1 : Wh0;
    const float* bv = layer ? bv1 : bv0;
    const float* xsrc = layer ? out : x;   // layer-1 input = y0 living in d_out
    float* hL = hbuf + (size_t)layer * 2 * BFE;

    // ---- one-time (per layer) W slice load into swizzled LDS ----
    __syncthreads();
    for (int idx = tid; idx < 8192; idx += NTHR) {
      const int k = idx >> 2, q = idx & 3;
      const float* src = (k < NF) ? (Wi + (size_t)k * NG) : (Wh + (size_t)(k - NF) * NG);
      const float4 v = *(const float4*)(src + q * NF + wg * 4);
      const int k4 = k >> 2, kk = k & 3;
      const float vv[4] = {v.x, v.y, v.z, v.w};
#pragma unroll
      for (int j = 0; j < 4; ++j) {
        const int c = q * 4 + j;
        const int slot = c ^ (k4 & 15);
        Wlds[(size_t)k4 * 64 + slot * 4 + kk] = vv[j];
      }
    }
    // zero h phase 0 (each WG zeroes its own 4 columns), load biases, reset state
    if (tid < 128) {
      const int b = tid >> 2, jp = tid & 3;
      hL[b * NF + wg * 4 + jp] = 0.0f;
    }
    float bias_q[4] = {0.f, 0.f, 0.f, 0.f};
    if (tid < 128) {
      const int jp = tid & 3;
#pragma unroll
      for (int q = 0; q < 4; ++q) bias_q[q] = bv[q * NF + wg * 4 + jp];
    }
    float c_reg = 0.0f, y_prev = 0.0f;
    __syncthreads();
    gridbar();  // h zeroed everywhere before anyone reads it

    for (int t = 0; t < NTT; ++t) {
      const float* hcur = hL + (size_t)(t & 1) * BFE;
      float* hnext = hL + (size_t)((t + 1) & 1) * BFE;

      float acc[8][8];
#pragma unroll
      for (int i = 0; i < 8; ++i)
#pragma unroll
        for (int j = 0; j < 8; ++j) acc[i][j] = 0.0f;

      // x part: U[b][k] = xsrc[b*TFE + t*NF + k], k in [0,1024)
      mm_part(xsrc + (size_t)t * NF + (size_t)(w * 8) * TFE + kb * 4, (size_t)TFE,
              0, kb, cq, Wlds, acc);
      // h part: U[b][1024+k] = hcur[b*NF + k]
      mm_part(hcur + (size_t)(w * 8) * NF + kb * 4, (size_t)NF,
              256, kb, cq, Wlds, acc);

      // butterfly all-reduce over kb (lane bits 0..4; cq bit untouched)
#pragma unroll
      for (int m = 1; m <= 16; m <<= 1) {
#pragma unroll
        for (int bi = 0; bi < 8; ++bi)
#pragma unroll
          for (int j = 0; j < 8; ++j) acc[bi][j] += __shfl_xor(acc[bi][j], m, 64);
      }

      // publish z[32][16] to LDS (one lane per (wave, cq))
      if (kb == 0) {
#pragma unroll
        for (int bi = 0; bi < 8; ++bi) {
          const int b = w * 8 + bi;
          *(float4*)&zbuf[b * 16 + cq * 8] =
              make_float4(acc[bi][0], acc[bi][1], acc[bi][2], acc[bi][3]);
          *(float4*)&zbuf[b * 16 + cq * 8 + 4] =
              make_float4(acc[bi][4], acc[bi][5], acc[bi][6], acc[bi][7]);
        }
      }
      __syncthreads();

      // gates: thread -> (b, jp); c-state in register
      if (tid < 128) {
        const int b = tid >> 2, jp = tid & 3;
        const int col = wg * 4 + jp;
        const float* zr = zbuf + b * 16;
        const float zi = zr[jp] + bias_q[0];
        const float zf = zr[4 + jp] + bias_q[1];
        const float zg = zr[8 + jp] + bias_q[2];
        const float zo = zr[12 + jp] + bias_q[3];
        const float cn = sigm(zf) * c_reg + sigm(zi) * tanh_s(zg);
        const float hn = sigm(zo) * tanh_s(cn);
        c_reg = cn;
        hnext[b * NF + col] = hn;
        if (layer == 0) {
          out[(size_t)b * TFE + (size_t)t * NF + col] = hn;   // y0 for layer 1
        } else {
          if (t > 0) out[(size_t)b * TFE + (size_t)(t - 1) * NF + col] = y_prev;
          y_prev = hn;  // delayed in-place overwrite of y0 row t
        }
      }
      gridbar();  // h(t+1) + y writes visible before next step's reads
    }
    if (layer == 1 && tid < 128) {
      const int b = tid >> 2, jp = tid & 3;
      out[(size_t)b * TFE + (size_t)(NTT - 1) * NF + wg * 4 + jp] = y_prev;
    }
  }
}

extern "C" void kernel_launch(void* const* d_in, const int* in_sizes, int n_in,
                              void* d_out, int out_size, void* d_ws, size_t ws_size,
                              hipStream_t stream) {
  (void)in_sizes; (void)n_in; (void)out_size; (void)ws_size;
  const float* x   = (const float*)d_in[0];
  const float* Wi0 = (const float*)d_in[1];
  const float* Wh0 = (const float*)d_in[2];
  const float* b0  = (const float*)d_in[3];
  const float* Wi1 = (const float*)d_in[4];
  const float* Wh1 = (const float*)d_in[5];
  const float* b1  = (const float*)d_in[6];
  float* out = (float*)d_out;

  float* hbuf = (float*)d_ws;                                    // [2][2][32][1024] fp32
  unsigned* bar = (unsigned*)((char*)d_ws + (size_t)2 * 2 * BFE * 4);

  hipMemsetAsync(bar, 0, 64, stream);  // barrier counter reset every call (replay-safe)

  static_assert(LDS_BYTES == 133120, "lds size");
  hipFuncSetAttribute((const void*)lstm_persist,
                      hipFuncAttributeMaxDynamicSharedMemorySize, LDS_BYTES);

  lstm_persist<<<dim3(NWG), dim3(NTHR), LDS_BYTES, stream>>>(
      x, Wi0, Wh0, b0, Wi1, Wh1, b1, out, hbuf, bar);
}

// Round 2
// 57381.030 us; speedup vs baseline: 1.1342x; 1.1342x over previous
//
#include <hip/hip_runtime.h>
#include <hip/hip_bf16.h>

// 2-layer LSTM, B=32 T=512 F=1024, fp32.
// Persistent kernel: 256 WGs x 256 thr, 1 WG/CU. Each WG owns 4 features x 4 gates
// = 16 columns of [Wi;Wh] (2048x16 fp32 = 128KB, LDS-resident, XOR-swizzled).
// Per step: z = [x_t ; h] @ Wslice  (U read from global/L2, W from LDS),
// 2-stage butterfly + LDS partial reduce, gates on 128 threads (c in regs),
// DISTRIBUTED-FLAG grid barrier (no single-counter atomic contention).

#define NB 32
#define NTT 512
#define NF 1024
#define NG 4096
#define TFE (NTT * NF)   // 524288 floats per batch row of x/out
#define BFE (NB * NF)    // 32768 floats per h phase
#define NWG 256
#define NTHR 256
#define W_FLOATS 32768
#define ZPSTRIDE 516          // 32*16 + 4 pad: spreads kb partials across banks
#define ZP_FLOATS (8 * ZPSTRIDE)
#define LDS_FLOATS (W_FLOATS + ZP_FLOATS)
#define LDS_BYTES (LDS_FLOATS * 4)

__device__ __forceinline__ float sigm(float v) { return 1.0f / (1.0f + __expf(-v)); }
__device__ __forceinline__ float tanh_s(float v) {
  float a = fabsf(v);
  float e = __expf(-2.0f * a);
  float t = (1.0f - e) / (1.0f + e);
  return v < 0.0f ? -t : t;
}

// One 8-chunk half of the per-step GEMM. ub already offset to (row w*8, col kb*4).
// W LDS layout: [k4][slot][kk] floats, slot = c ^ (k4&15)  (16B-slot XOR swizzle).
__device__ __forceinline__ void mm_part(const float* __restrict__ ub, size_t rstride,
                                        int k4base, int kb, int cq,
                                        const float* __restrict__ Wlds, float acc[8][8]) {
#pragma unroll 4
  for (int ci = 0; ci < 8; ++ci) {
    const int k4 = k4base + ci * 32 + kb;
    float4 u[8];
#pragma unroll
    for (int bi = 0; bi < 8; ++bi)
      u[bi] = *(const float4*)(ub + (size_t)bi * rstride + ci * 128);
    float4 wv[8];
    const int swz = k4 & 15;
#pragma unroll
    for (int j = 0; j < 8; ++j) {
      const int c = cq * 8 + j;
      wv[j] = *(const float4*)(Wlds + (size_t)k4 * 64 + (size_t)((c ^ swz) * 4));
    }
#pragma unroll
    for (int bi = 0; bi < 8; ++bi) {
#pragma unroll
      for (int j = 0; j < 8; ++j) {
        acc[bi][j] = fmaf(u[bi].x, wv[j].x, acc[bi][j]);
        acc[bi][j] = fmaf(u[bi].y, wv[j].y, acc[bi][j]);
        acc[bi][j] = fmaf(u[bi].z, wv[j].z, acc[bi][j]);
        acc[bi][j] = fmaf(u[bi].w, wv[j].w, acc[bi][j]);
      }
    }
  }
}

__global__ __launch_bounds__(NTHR, 1) void lstm_persist(
    const float* __restrict__ x,
    const float* __restrict__ Wi0, const float* __restrict__ Wh0, const float* __restrict__ bv0,
    const float* __restrict__ Wi1, const float* __restrict__ Wh1, const float* __restrict__ bv1,
    float* __restrict__ out, float* __restrict__ hbuf, unsigned* __restrict__ bar) {
  extern __shared__ float lds[];
  float* Wlds = lds;              // [512][16][4] swizzled = 32768 floats (128KB)
  float* zpart = lds + W_FLOATS;  // [8][ZPSTRIDE]
  const int wg = blockIdx.x;
  const int tid = threadIdx.x;
  const int w = tid >> 6;          // wave id -> batch octet
  const int lane = tid & 63;
  const int cq = lane >> 5;        // column half (0: gates i,f ; 1: gates g,o)
  const int kb = lane & 31;        // K-split slot within wave
  unsigned gen = 0;

  // Distributed-flag grid barrier: each WG publishes its own generation flag
  // (agent-scope store, no RMW contention); wave 0 polls all 256 flags.
  auto gridbar = [&]() {
    __threadfence();     // release: prior global writes visible device-wide
    __syncthreads();
    ++gen;
    if (tid < 64) {
      if (tid == 0)
        __hip_atomic_store(&bar[wg], gen, __ATOMIC_RELAXED, __HIP_MEMORY_SCOPE_AGENT);
      for (;;) {
        int ok = 1;
#pragma unroll
        for (int q = 0; q < 4; ++q) {
          unsigned v = __hip_atomic_load(&bar[tid + q * 64], __ATOMIC_RELAXED,
                                         __HIP_MEMORY_SCOPE_AGENT);
          ok &= (v >= gen);
        }
        if (__all(ok)) break;
        __builtin_amdgcn_s_sleep(1);
      }
    }
    __syncthreads();
    __threadfence();     // acquire: invalidate stale cached lines
  };

  for (int layer = 0; layer < 2; ++layer) {
    const float* Wi = layer ? Wi1 : Wi0;
    const float* Wh = layer ? Wh1 : Wh0;
    const float* bv = layer ? bv1 : bv0;
    const float* xsrc = layer ? out : x;   // layer-1 input = y0 living in d_out
    float* hL = hbuf + (size_t)layer * 2 * BFE;

    // ---- one-time (per layer) W slice load into swizzled LDS ----
    __syncthreads();
    for (int idx = tid; idx < 8192; idx += NTHR) {
      const int k = idx >> 2, q = idx & 3;
      const float* src = (k < NF) ? (Wi + (size_t)k * NG) : (Wh + (size_t)(k - NF) * NG);
      const float4 v = *(const float4*)(src + q * NF + wg * 4);
      const int k4 = k >> 2, kk = k & 3;
      const float vv[4] = {v.x, v.y, v.z, v.w};
#pragma unroll
      for (int j = 0; j < 4; ++j) {
        const int c = q * 4 + j;
        const int slot = c ^ (k4 & 15);
        Wlds[(size_t)k4 * 64 + slot * 4 + kk] = vv[j];
      }
    }
    // zero h phase 0 (each WG zeroes its own 4 columns), load biases, reset state
    if (tid < 128) {
      const int b = tid >> 2, jp = tid & 3;
      hL[b * NF + wg * 4 + jp] = 0.0f;
    }
    float bias_q[4] = {0.f, 0.f, 0.f, 0.f};
    if (tid < 128) {
      const int jp = tid & 3;
#pragma unroll
      for (int q = 0; q < 4; ++q) bias_q[q] = bv[q * NF + wg * 4 + jp];
    }
    float c_reg = 0.0f, y_prev = 0.0f;
    __syncthreads();
    gridbar();  // h zeroed everywhere before anyone reads it

    for (int t = 0; t < NTT; ++t) {
      const float* hcur = hL + (size_t)(t & 1) * BFE;
      float* hnext = hL + (size_t)((t + 1) & 1) * BFE;

      float acc[8][8];
#pragma unroll
      for (int i = 0; i < 8; ++i)
#pragma unroll
        for (int j = 0; j < 8; ++j) acc[i][j] = 0.0f;

      // x part: U[b][k] = xsrc[b*TFE + t*NF + k], k in [0,1024)
      mm_part(xsrc + (size_t)t * NF + (size_t)(w * 8) * TFE + kb * 4, (size_t)TFE,
              0, kb, cq, Wlds, acc);
      // h part: U[b][1024+k] = hcur[b*NF + k]
      mm_part(hcur + (size_t)(w * 8) * NF + kb * 4, (size_t)NF,
              256, kb, cq, Wlds, acc);

      // 2-stage butterfly over kb bits {3,4}: lanes kb<8 hold 4-way partials
#pragma unroll
      for (int m = 8; m <= 16; m <<= 1) {
#pragma unroll
        for (int bi = 0; bi < 8; ++bi)
#pragma unroll
          for (int j = 0; j < 8; ++j) acc[bi][j] += __shfl_xor(acc[bi][j], m, 64);
      }

      // publish 8 kb-partials to LDS
      if (kb < 8) {
#pragma unroll
        for (int bi = 0; bi < 8; ++bi) {
          const int b = w * 8 + bi;
          float* zp = zpart + kb * ZPSTRIDE + b * 16 + cq * 8;
          *(float4*)zp = make_float4(acc[bi][0], acc[bi][1], acc[bi][2], acc[bi][3]);
          *(float4*)(zp + 4) = make_float4(acc[bi][4], acc[bi][5], acc[bi][6], acc[bi][7]);
        }
      }
      __syncthreads();

      // gates: thread -> (b, jp); sum 8 partials; c-state in register
      if (tid < 128) {
        const int b = tid >> 2, jp = tid & 3;
        const int col = wg * 4 + jp;
        float zi = 0.f, zf = 0.f, zg = 0.f, zo = 0.f;
#pragma unroll
        for (int kp = 0; kp < 8; ++kp) {
          const float* zr = zpart + kp * ZPSTRIDE + b * 16;
          zi += zr[jp]; zf += zr[4 + jp]; zg += zr[8 + jp]; zo += zr[12 + jp];
        }
        zi += bias_q[0]; zf += bias_q[1]; zg += bias_q[2]; zo += bias_q[3];
        const float cn = sigm(zf) * c_reg + sigm(zi) * tanh_s(zg);
        const float hn = sigm(zo) * tanh_s(cn);
        c_reg = cn;
        hnext[b * NF + col] = hn;
        if (layer == 0) {
          out[(size_t)b * TFE + (size_t)t * NF + col] = hn;   // y0 for layer 1
        } else {
          if (t > 0) out[(size_t)b * TFE + (size_t)(t - 1) * NF + col] = y_prev;
          y_prev = hn;  // delayed in-place overwrite of y0 row t
        }
      }
      gridbar();  // h(t+1) + y writes visible before next step's reads
    }
    if (layer == 1 && tid < 128) {
      const int b = tid >> 2, jp = tid & 3;
      out[(size_t)b * TFE + (size_t)(NTT - 1) * NF + wg * 4 + jp] = y_prev;
    }
  }
}

extern "C" void kernel_launch(void* const* d_in, const int* in_sizes, int n_in,
                              void* d_out, int out_size, void* d_ws, size_t ws_size,
                              hipStream_t stream) {
  (void)in_sizes; (void)n_in; (void)out_size; (void)ws_size;
  const float* x   = (const float*)d_in[0];
  const float* Wi0 = (const float*)d_in[1];
  const float* Wh0 = (const float*)d_in[2];
  const float* b0  = (const float*)d_in[3];
  const float* Wi1 = (const float*)d_in[4];
  const float* Wh1 = (const float*)d_in[5];
  const float* b1  = (const float*)d_in[6];
  float* out = (float*)d_out;

  float* hbuf = (float*)d_ws;                                    // [2][2][32][1024] fp32
  unsigned* bar = (unsigned*)((char*)d_ws + (size_t)2 * 2 * BFE * 4);

  hipMemsetAsync(bar, 0, 4096, stream);  // flag array reset every call (replay-safe)

  hipFuncSetAttribute((const void*)lstm_persist,
                      hipFuncAttributeMaxDynamicSharedMemorySize, LDS_BYTES);

  lstm_persist<<<dim3(NWG), dim3(NTHR), LDS_BYTES, stream>>>(
      x, Wi0, Wh0, b0, Wi1, Wh1, b1, out, hbuf, bar);
}

// Round 3
// 18528.632 us; speedup vs baseline: 3.5126x; 3.0969x over previous
//
#include <hip/hip_runtime.h>
#include <hip/hip_bf16.h>

// 2-layer LSTM, B=32 T=512 F=1024, fp32.
// Persistent kernel: 256 WGs x 256 thr, 1 WG/CU. Each WG owns 4 features x 4 gates
// = 16 columns of [Wi;Wh] (2048x16 fp32 = 128KB, LDS-resident, XOR-swizzled).
// Per step: z = [x_t ; h] @ Wslice. x/U from L2-cached plain loads; h exchanged
// via sc0sc1 (L2-bypass) stores/loads so NO per-step threadfence (no buffer_wbl2 /
// buffer_inv full-L2 ops — that was the 50us/step stall). Distributed-flag grid
// barrier with per-wave vmcnt drain only. Full __threadfence only at the
// layer-0 -> layer-1 boundary (y0 handoff through L2 writeback+inv, 2 total).

#define NB 32
#define NTT 512
#define NF 1024
#define NG 4096
#define TFE (NTT * NF)   // 524288 floats per batch row of x/out
#define BFE (NB * NF)    // 32768 floats per h phase
#define NWG 256
#define NTHR 256
#define W_FLOATS 32768
#define ZBSTRIDE 132          // 8*16 + 4 pad per batch row: 2-way-free gate reads
#define ZP_FLOATS (NB * ZBSTRIDE)
#define LDS_FLOATS (W_FLOATS + ZP_FLOATS)
#define LDS_BYTES (LDS_FLOATS * 4)   // 147968 B

__device__ __forceinline__ float sigm(float v) { return 1.0f / (1.0f + __expf(-v)); }
__device__ __forceinline__ float tanh_s(float v) {
  float a = fabsf(v);
  float e = __expf(-2.0f * a);
  float t = (1.0f - e) / (1.0f + e);
  return v < 0.0f ? -t : t;
}

// 8x8 rank-4 FMA block: u[bi] x W-cols (cq*8..+7) at K-chunk k4.
__device__ __forceinline__ void fma8(const float4 u[8], int k4, int cq,
                                     const float* __restrict__ Wlds, float acc[8][8]) {
  const int swz = k4 & 15;
  float4 wv[8];
#pragma unroll
  for (int j = 0; j < 8; ++j)
    wv[j] = *(const float4*)(Wlds + (size_t)k4 * 64 + (size_t)(((cq * 8 + j) ^ swz) * 4));
#pragma unroll
  for (int bi = 0; bi < 8; ++bi) {
#pragma unroll
    for (int j = 0; j < 8; ++j) {
      acc[bi][j] = fmaf(u[bi].x, wv[j].x, acc[bi][j]);
      acc[bi][j] = fmaf(u[bi].y, wv[j].y, acc[bi][j]);
      acc[bi][j] = fmaf(u[bi].z, wv[j].z, acc[bi][j]);
      acc[bi][j] = fmaf(u[bi].w, wv[j].w, acc[bi][j]);
    }
  }
}

// x part: plain (L2-cacheable) loads, compiler-scheduled.
__device__ __forceinline__ void mm_x(const float* __restrict__ ub, size_t rstride,
                                     int kb, int cq, const float* __restrict__ Wlds,
                                     float acc[8][8]) {
#pragma unroll 4
  for (int ci = 0; ci < 8; ++ci) {
    float4 u[8];
#pragma unroll
    for (int bi = 0; bi < 8; ++bi)
      u[bi] = *(const float4*)(ub + (size_t)bi * rstride + ci * 128);
    fma8(u, ci * 32 + kb, cq, Wlds, acc);
  }
}

// h part: L2-bypass (sc0 sc1) loads — always coherent vs other XCDs' h writes.
__device__ __forceinline__ void loadh8(float4 u[8], const float* __restrict__ p) {
#pragma unroll
  for (int bi = 0; bi < 8; ++bi)
    asm volatile("global_load_dwordx4 %0, %1, off sc0 sc1"
                 : "=v"(u[bi]) : "v"(p + (size_t)bi * NF) : "memory");
}

__device__ __forceinline__ void mm_h(const float* __restrict__ ub,
                                     int kb, int cq, const float* __restrict__ Wlds,
                                     float acc[8][8]) {
  float4 u0[8], u1[8];
  loadh8(u0, ub);            // ci=0 batch in flight
#pragma unroll
  for (int ci = 0; ci < 8; ++ci) {
    if (ci < 7) {            // issue next batch before consuming current
      if (ci & 1) loadh8(u0, ub + (ci + 1) * 128);
      else        loadh8(u1, ub + (ci + 1) * 128);
      asm volatile("s_waitcnt vmcnt(8)" ::: "memory");
    } else {
      asm volatile("s_waitcnt vmcnt(0)" ::: "memory");
    }
    __builtin_amdgcn_sched_barrier(0);   // rule #18: pin FMAs after the waitcnt
    fma8((ci & 1) ? u1 : u0, 256 + ci * 32 + kb, cq, Wlds, acc);
  }
}

__global__ __launch_bounds__(NTHR, 1) void lstm_persist(
    const float* __restrict__ x,
    const float* __restrict__ Wi0, const float* __restrict__ Wh0, const float* __restrict__ bv0,
    const float* __restrict__ Wi1, const float* __restrict__ Wh1, const float* __restrict__ bv1,
    float* __restrict__ out, float* __restrict__ hbuf, unsigned* __restrict__ bar) {
  extern __shared__ float lds[];
  float* Wlds = lds;              // [512][16][4] swizzled = 32768 floats (128KB)
  float* zpart = lds + W_FLOATS;  // [32][ZBSTRIDE]
  const int wg = blockIdx.x;
  const int tid = threadIdx.x;
  const int w = tid >> 6;          // wave id -> batch octet
  const int lane = tid & 63;
  const int cq = lane >> 5;        // column half (0: gates i,f ; 1: gates g,o)
  const int kb = lane & 31;        // K-split slot within wave
  unsigned gen = 0;

  // Distributed-flag grid barrier. NO cache maintenance: per-wave vmcnt drain
  // guarantees this WG's bypass (sc0sc1) h-stores reached the coherence point
  // before the flag store; readers use bypass loads, so no inv needed.
  auto gridbar = [&]() {
    asm volatile("s_waitcnt vmcnt(0) lgkmcnt(0)" ::: "memory");
    __syncthreads();
    ++gen;
    if (tid < 64) {
      if (tid == 0)
        __hip_atomic_store(&bar[wg], gen, __ATOMIC_RELAXED, __HIP_MEMORY_SCOPE_AGENT);
      for (;;) {
        int ok = 1;
#pragma unroll
        for (int q = 0; q < 4; ++q) {
          unsigned v = __hip_atomic_load(&bar[tid + q * 64], __ATOMIC_RELAXED,
                                         __HIP_MEMORY_SCOPE_AGENT);
          ok &= (v >= gen);
        }
        if (__all(ok)) break;
        __builtin_amdgcn_s_sleep(1);
      }
    }
    __syncthreads();
  };

  for (int layer = 0; layer < 2; ++layer) {
    const float* Wi = layer ? Wi1 : Wi0;
    const float* Wh = layer ? Wh1 : Wh0;
    const float* bv = layer ? bv1 : bv0;
    const float* xsrc = layer ? out : x;   // layer-1 input = y0 living in d_out
    float* hL = hbuf + (size_t)layer * 2 * BFE;

    if (layer == 1) {
      // y0 handoff across XCDs: flush dirty y0 (wbl2), barrier, then drop
      // stale clean lines (inv) before any y0 read. Only 2 full fences total.
      __threadfence();
      gridbar();
      __threadfence();
    }

    // ---- one-time (per layer) W slice load into swizzled LDS ----
    __syncthreads();
    for (int idx = tid; idx < 8192; idx += NTHR) {
      const int k = idx >> 2, q = idx & 3;
      const float* src = (k < NF) ? (Wi + (size_t)k * NG) : (Wh + (size_t)(k - NF) * NG);
      const float4 v = *(const float4*)(src + q * NF + wg * 4);
      const int k4 = k >> 2, kk = k & 3;
      const float vv[4] = {v.x, v.y, v.z, v.w};
#pragma unroll
      for (int j = 0; j < 4; ++j) {
        const int c = q * 4 + j;
        const int slot = c ^ (k4 & 15);
        Wlds[(size_t)k4 * 64 + slot * 4 + kk] = vv[j];
      }
    }
    // zero h phase 0 (bypass stores, matching the bypass-read protocol)
    if (tid < 128) {
      const int b = tid >> 2, jp = tid & 3;
      __hip_atomic_store(&hL[b * NF + wg * 4 + jp], 0.0f,
                         __ATOMIC_RELAXED, __HIP_MEMORY_SCOPE_AGENT);
    }
    float bias_q[4] = {0.f, 0.f, 0.f, 0.f};
    if (tid < 128) {
      const int jp = tid & 3;
#pragma unroll
      for (int q = 0; q < 4; ++q) bias_q[q] = bv[q * NF + wg * 4 + jp];
    }
    float c_reg = 0.0f, y_prev = 0.0f;
    __syncthreads();
    gridbar();  // h zeroed everywhere before anyone reads it

    for (int t = 0; t < NTT; ++t) {
      const float* hcur = hL + (size_t)(t & 1) * BFE;
      float* hnext = hL + (size_t)((t + 1) & 1) * BFE;

      float acc[8][8];
#pragma unroll
      for (int i = 0; i < 8; ++i)
#pragma unroll
        for (int j = 0; j < 8; ++j) acc[i][j] = 0.0f;

      // x part: U[b][k] = xsrc[b*TFE + t*NF + k]
      mm_x(xsrc + (size_t)t * NF + (size_t)(w * 8) * TFE + kb * 4, (size_t)TFE,
           kb, cq, Wlds, acc);
      // h part: U[b][1024+k] = hcur[b*NF + k]  (coherent bypass loads)
      mm_h(hcur + (size_t)(w * 8) * NF + kb * 4, kb, cq, Wlds, acc);

      // 2-stage butterfly over kb bits {3,4}: lanes kb<8 hold 4-way partials
#pragma unroll
      for (int m = 8; m <= 16; m <<= 1) {
#pragma unroll
        for (int bi = 0; bi < 8; ++bi)
#pragma unroll
          for (int j = 0; j < 8; ++j) acc[bi][j] += __shfl_xor(acc[bi][j], m, 64);
      }

      // publish 8 kb-partials to LDS: zpart[b][kp][16], per-b stride 132
      if (kb < 8) {
#pragma unroll
        for (int bi = 0; bi < 8; ++bi) {
          const int b = w * 8 + bi;
          float* zp = zpart + b * ZBSTRIDE + kb * 16 + cq * 8;
          *(float4*)zp = make_float4(acc[bi][0], acc[bi][1], acc[bi][2], acc[bi][3]);
          *(float4*)(zp + 4) = make_float4(acc[bi][4], acc[bi][5], acc[bi][6], acc[bi][7]);
        }
      }
      __syncthreads();

      // gates: thread -> (b, jp); sum 8 partials; c-state in register
      if (tid < 128) {
        const int b = tid >> 2, jp = tid & 3;
        const int col = wg * 4 + jp;
        const float* zr = zpart + b * ZBSTRIDE;
        float zi = 0.f, zf = 0.f, zg = 0.f, zo = 0.f;
#pragma unroll
        for (int kp = 0; kp < 8; ++kp) {
          zi += zr[kp * 16 + jp];
          zf += zr[kp * 16 + 4 + jp];
          zg += zr[kp * 16 + 8 + jp];
          zo += zr[kp * 16 + 12 + jp];
        }
        zi += bias_q[0]; zf += bias_q[1]; zg += bias_q[2]; zo += bias_q[3];
        const float cn = sigm(zf) * c_reg + sigm(zi) * tanh_s(zg);
        const float hn = sigm(zo) * tanh_s(cn);
        c_reg = cn;
        // h exchange: bypass store (write-through to coherence point)
        __hip_atomic_store(&hnext[b * NF + col], hn,
                           __ATOMIC_RELAXED, __HIP_MEMORY_SCOPE_AGENT);
        if (layer == 0) {
          out[(size_t)b * TFE + (size_t)t * NF + col] = hn;   // y0 for layer 1
        } else {
          if (t > 0) out[(size_t)b * TFE + (size_t)(t - 1) * NF + col] = y_prev;
          y_prev = hn;  // delayed in-place overwrite of y0 row t
        }
      }
      gridbar();  // h(t+1) visible (via vmcnt drain) before next step's reads
    }
    if (layer == 1 && tid < 128) {
      const int b = tid >> 2, jp = tid & 3;
      out[(size_t)b * TFE + (size_t)(NTT - 1) * NF + wg * 4 + jp] = y_prev;
    }
  }
}

extern "C" void kernel_launch(void* const* d_in, const int* in_sizes, int n_in,
                              void* d_out, int out_size, void* d_ws, size_t ws_size,
                              hipStream_t stream) {
  (void)in_sizes; (void)n_in; (void)out_size; (void)ws_size;
  const float* x   = (const float*)d_in[0];
  const float* Wi0 = (const float*)d_in[1];
  const float* Wh0 = (const float*)d_in[2];
  const float* b0  = (const float*)d_in[3];
  const float* Wi1 = (const float*)d_in[4];
  const float* Wh1 = (const float*)d_in[5];
  const float* b1  = (const float*)d_in[6];
  float* out = (float*)d_out;

  float* hbuf = (float*)d_ws;                                    // [2][2][32][1024] fp32
  unsigned* bar = (unsigned*)((char*)d_ws + (size_t)2 * 2 * BFE * 4);

  hipMemsetAsync(bar, 0, 4096, stream);  // flag array reset every call (replay-safe)

  hipFuncSetAttribute((const void*)lstm_persist,
                      hipFuncAttributeMaxDynamicSharedMemorySize, LDS_BYTES);

  lstm_persist<<<dim3(NWG), dim3(NTHR), LDS_BYTES, stream>>>(
      x, Wi0, Wh0, b0, Wi1, Wh1, b1, out, hbuf, bar);
}

// Round 5
// 17520.612 us; speedup vs baseline: 3.7147x; 1.0575x over previous
//
#include <hip/hip_runtime.h>
#include <hip/hip_bf16.h>
#include <hip/hip_fp16.h>

// 2-layer LSTM, B=32 T=512 F=1024. MFMA f16 core.
// 256 WGs x 256 thr (1 WG/CU). WG owns 16 cols of [Wi;Wh] = {gate q, feat wg*4+j}.
// W: f16 in LDS, pre-swizzled to mfma_f32_16x16x32_f16 B-frag order.
// 4 waves split K=2048 into quarters; waves 0,1: x/y0 part (fp32 global + cvt),
// waves 2,3: h part (f16, staged per step into XOR-swizzled LDS via sc0sc1 loads).
// Cross-wave reduce via padded LDS; gates on 64 threads; h ring = packed f16
// bypass stores; distributed-flag grid barrier (R3-proven skeleton).

typedef _Float16 f16x8 __attribute__((ext_vector_type(8)));
typedef __fp16 fp16x2 __attribute__((ext_vector_type(2)));
typedef float f32x4 __attribute__((ext_vector_type(4)));

#define NB 32
#define NTT 512
#define NF 1024
#define NG 4096
#define TFE (NTT * NF)
#define NWG 256
#define NTHR 256

#define W_BYTES 65536                 // [64 s][64 lane][8 f16]
#define H_BYTES 65536                 // [32 b][1024 f16], 16B-slot XOR swizzle
#define ZSEG 272                      // 16 rows * 17 (pad)
#define Z_FLOATS (8 * ZSEG)
#define LDS_BYTES (W_BYTES + H_BYTES + Z_FLOATS * 4)   // 139776

__device__ __forceinline__ float sigm(float v) { return 1.0f / (1.0f + __expf(-v)); }
__device__ __forceinline__ float tanh_s(float v) {
  float a = fabsf(v);
  float e = __expf(-2.0f * a);
  float t = (1.0f - e) / (1.0f + e);
  return v < 0.0f ? -t : t;
}

// pack 2 floats -> u32 of 2 f16 (RTZ)
__device__ __forceinline__ unsigned pk(float a, float b) {
  union { fp16x2 h2; unsigned u; } c;
  c.h2 = __builtin_amdgcn_cvt_pkrtz(a, b);
  return c.u;
}

__device__ __forceinline__ f16x8 cvt8(f32x4 lo, f32x4 hi) {
  union { unsigned u[4]; f16x8 h8; } u;
  u.u[0] = pk(lo[0], lo[1]);
  u.u[1] = pk(lo[2], lo[3]);
  u.u[2] = pk(hi[0], hi[1]);
  u.u[3] = pk(hi[2], hi[3]);
  return u.h8;
}

__global__ __launch_bounds__(NTHR, 1) void lstm_persist(
    const float* __restrict__ x,
    const float* __restrict__ Wi0, const float* __restrict__ Wh0, const float* __restrict__ bv0,
    const float* __restrict__ Wi1, const float* __restrict__ Wh1, const float* __restrict__ bv1,
    float* __restrict__ out, unsigned short* __restrict__ hring_u16,
    unsigned* __restrict__ bar) {
  extern __shared__ char lds[];
  f16x8* Wl = (f16x8*)lds;                       // Wl[s*64 + lane]
  char* Hl = lds + W_BYTES;                      // swizzled h tile
  float* Zr = (float*)(lds + W_BYTES + H_BYTES); // Zr[(w*2+mt)*ZSEG + row*17 + n]

  const int wg = blockIdx.x;
  const int tid = threadIdx.x;
  const int w = tid >> 6;          // wave id: 0,1 -> x-part K half; 2,3 -> h-part
  const int lane = tid & 63;
  const int r = lane & 15;         // fragment row/col index
  const int g = lane >> 4;         // k-group
  unsigned gen = 0;

  auto gridbar = [&]() {
    asm volatile("s_waitcnt vmcnt(0) lgkmcnt(0)" ::: "memory");
    __syncthreads();
    ++gen;
    if (tid < 64) {
      if (tid == 0)
        __hip_atomic_store(&bar[wg], gen, __ATOMIC_RELAXED, __HIP_MEMORY_SCOPE_AGENT);
      for (;;) {
        int ok = 1;
#pragma unroll
        for (int q = 0; q < 4; ++q) {
          unsigned v = __hip_atomic_load(&bar[tid + q * 64], __ATOMIC_RELAXED,
                                         __HIP_MEMORY_SCOPE_AGENT);
          ok &= (v >= gen);
        }
        if (__all(ok)) break;
        __builtin_amdgcn_s_sleep(1);
      }
    }
    __syncthreads();
  };

  for (int layer = 0; layer < 2; ++layer) {
    const float* Wi = layer ? Wi1 : Wi0;
    const float* Wh = layer ? Wh1 : Wh0;
    const float* bv = layer ? bv1 : bv0;
    const float* xsrc = layer ? out : x;   // layer-1 input = y0 (fp32, in d_out)
    unsigned* hu = (unsigned*)(hring_u16 + (size_t)layer * 2 * NB * NF); // packed f16 ring

    if (layer == 1) {
      // y0 handoff across XCDs: wbl2 flush, barrier, inv. (2 full fences total)
      __threadfence();
      gridbar();
      __threadfence();
    }
    __syncthreads();  // prior Wl reads done (gridbar) — safe to overwrite

    // ---- stage W slice -> f16 LDS in B-fragment order ----
    // k -> (s=k>>5, kg=(k>>3)&3, jj=k&7); col n=q*4+j -> lane L=kg*16+n
    for (int idx = tid; idx < 8192; idx += NTHR) {
      const int k = idx >> 2, q = idx & 3;
      const float* src = (k < NF) ? (Wi + (size_t)k * NG) : (Wh + (size_t)(k - NF) * NG);
      const f32x4 v = *(const f32x4*)(src + q * NF + wg * 4);
      const int s = k >> 5, kg = (k >> 3) & 3, jj = k & 7;
#pragma unroll
      for (int j = 0; j < 4; ++j) {
        _Float16* dst = (_Float16*)&Wl[(s * 64) + (kg * 16) + (q * 4 + j)];
        dst[jj] = (_Float16)v[j];
      }
    }
    // zero h ring phase 0 (packed f16, bypass stores)
    if (tid < 64) {
      const int b = tid >> 1, jp2 = tid & 1;
      __hip_atomic_store(&hu[b * 512 + wg * 2 + jp2], 0u,
                         __ATOMIC_RELAXED, __HIP_MEMORY_SCOPE_AGENT);
    }
    float bias[4][2];
    if (tid < 64) {
      const int jp2 = tid & 1;
#pragma unroll
      for (int q = 0; q < 4; ++q) {
        bias[q][0] = bv[q * NF + wg * 4 + 2 * jp2];
        bias[q][1] = bv[q * NF + wg * 4 + 2 * jp2 + 1];
      }
    }
    float cst[2] = {0.f, 0.f};
    float2 y_prev = {0.f, 0.f};
    __syncthreads();
    gridbar();  // W staged + h zeroed everywhere

    for (int t = 0; t < NTT; ++t) {
      // ---- stage h(t) into swizzled LDS (coherent bypass loads, once/step) ----
      {
        const char* hc = (const char*)hu + (size_t)(t & 1) * NB * NF * 2;
        const int b = tid >> 3, fg = tid & 7;
        const char* base = hc + b * 2048 + fg * 256;
        float4 tmp[16];
#pragma unroll
        for (int i = 0; i < 16; ++i)
          asm volatile("global_load_dwordx4 %0, %1, off sc0 sc1"
                       : "=v"(tmp[i]) : "v"(base + i * 16) : "memory");
        asm volatile("s_waitcnt vmcnt(0)" ::: "memory");
        __builtin_amdgcn_sched_barrier(0);
        const int swz = (b & 7) << 4;
#pragma unroll
        for (int i = 0; i < 16; ++i) {
          const int featB = fg * 256 + i * 16;     // byte offset in row
          *(float4*)(Hl + b * 2048 + (featB ^ swz)) = tmp[i];
        }
      }
      __syncthreads();

      // ---- MFMA core: each wave = K-quarter, 2 M-tiles, 16 K-steps ----
      f32x4 acc0 = {0.f, 0.f, 0.f, 0.f}, acc1 = {0.f, 0.f, 0.f, 0.f};
      if (w < 2) {
        const float* p0 = xsrc + (size_t)r * TFE + (size_t)t * NF + w * 512 + g * 8;
        const float* p1 = xsrc + (size_t)(16 + r) * TFE + (size_t)t * NF + w * 512 + g * 8;
#pragma unroll
        for (int ks = 0; ks < 16; ++ks) {
          const f16x8 B = Wl[(w * 16 + ks) * 64 + lane];
          const f32x4 a0l = *(const f32x4*)(p0 + ks * 32);
          const f32x4 a0h = *(const f32x4*)(p0 + ks * 32 + 4);
          const f32x4 a1l = *(const f32x4*)(p1 + ks * 32);
          const f32x4 a1h = *(const f32x4*)(p1 + ks * 32 + 4);
          acc0 = __builtin_amdgcn_mfma_f32_16x16x32_f16(cvt8(a0l, a0h), B, acc0, 0, 0, 0);
          acc1 = __builtin_amdgcn_mfma_f32_16x16x32_f16(cvt8(a1l, a1h), B, acc1, 0, 0, 0);
        }
      } else {
        const int swz = (r & 7) << 4;
#pragma unroll
        for (int ks = 0; ks < 16; ++ks) {
          const f16x8 B = Wl[(w * 16 + ks) * 64 + lane];
          const int fB = ((w - 2) * 512 + ks * 32 + g * 8) * 2;
          const f16x8 A0 = *(const f16x8*)(Hl + r * 2048 + (fB ^ swz));
          const f16x8 A1 = *(const f16x8*)(Hl + (16 + r) * 2048 + (fB ^ swz));
          acc0 = __builtin_amdgcn_mfma_f32_16x16x32_f16(A0, B, acc0, 0, 0, 0);
          acc1 = __builtin_amdgcn_mfma_f32_16x16x32_f16(A1, B, acc1, 0, 0, 0);
        }
      }

      // ---- cross-wave K reduction via LDS ----
      // C/D layout (verified): col n = lane&15, row = (lane>>4)*4 + reg
      {
        float* zb0 = Zr + (w * 2 + 0) * ZSEG;
        float* zb1 = Zr + (w * 2 + 1) * ZSEG;
#pragma unroll
        for (int reg = 0; reg < 4; ++reg) {
          zb0[(g * 4 + reg) * 17 + r] = acc0[reg];
          zb1[(g * 4 + reg) * 17 + r] = acc1[reg];
        }
      }
      __syncthreads();

      // ---- gates: 64 threads, 2 feats each; c-state in regs ----
      if (tid < 64) {
        const int b = tid >> 1, jp2 = tid & 1;
        const int mt = b >> 4, row = b & 15;
        float hv[2];
#pragma unroll
        for (int e = 0; e < 2; ++e) {
          float zq[4];
#pragma unroll
          for (int q = 0; q < 4; ++q) {
            const int n = q * 4 + 2 * jp2 + e;
            float sum = bias[q][e];
#pragma unroll
            for (int ww = 0; ww < 4; ++ww)
              sum += Zr[(ww * 2 + mt) * ZSEG + row * 17 + n];
            zq[q] = sum;
          }
          const float cn = sigm(zq[1]) * cst[e] + sigm(zq[0]) * tanh_s(zq[2]);
          hv[e] = sigm(zq[3]) * tanh_s(cn);
          cst[e] = cn;
        }
        // h ring: packed f16 bypass store
        __hip_atomic_store(&hu[((t + 1) & 1) * NB * 512 + b * 512 + wg * 2 + jp2],
                           pk(hv[0], hv[1]), __ATOMIC_RELAXED, __HIP_MEMORY_SCOPE_AGENT);
        // outputs (fp32)
        float* orow = out + (size_t)b * TFE + (size_t)wg * 4 + 2 * jp2;
        if (layer == 0) {
          *(float2*)(orow + (size_t)t * NF) = make_float2(hv[0], hv[1]);
        } else {
          if (t > 0) *(float2*)(orow + (size_t)(t - 1) * NF) = y_prev;
          y_prev = make_float2(hv[0], hv[1]);
        }
      }
      gridbar();  // h(t+1) drained to coherence point before next step reads
    }
    if (layer == 1 && tid < 64) {
      const int b = tid >> 1, jp2 = tid & 1;
      *(float2*)(out + (size_t)b * TFE + (size_t)(NTT - 1) * NF + wg * 4 + 2 * jp2) = y_prev;
    }
  }
}

extern "C" void kernel_launch(void* const* d_in, const int* in_sizes, int n_in,
                              void* d_out, int out_size, void* d_ws, size_t ws_size,
                              hipStream_t stream) {
  (void)in_sizes; (void)n_in; (void)out_size; (void)ws_size;
  const float* x   = (const float*)d_in[0];
  const float* Wi0 = (const float*)d_in[1];
  const float* Wh0 = (const float*)d_in[2];
  const float* b0  = (const float*)d_in[3];
  const float* Wi1 = (const float*)d_in[4];
  const float* Wh1 = (const float*)d_in[5];
  const float* b1  = (const float*)d_in[6];
  float* out = (float*)d_out;

  unsigned short* hring = (unsigned short*)d_ws;   // [2 layers][2 phases][32][1024] f16
  unsigned* bar = (unsigned*)((char*)d_ws + (size_t)2 * 2 * NB * NF * 2);  // +256KB

  (void)hipMemsetAsync(bar, 0, 4096, stream);  // flag array reset (replay-safe)

  (void)hipFuncSetAttribute((const void*)lstm_persist,
                            hipFuncAttributeMaxDynamicSharedMemorySize, LDS_BYTES);

  lstm_persist<<<dim3(NWG), dim3(NTHR), LDS_BYTES, stream>>>(
      x, Wi0, Wh0, b0, Wi1, Wh1, b1, out, hring, bar);
}

// Round 6
// 11143.243 us; speedup vs baseline: 5.8407x; 1.5723x over previous
//
#include <hip/hip_runtime.h>
#include <hip/hip_bf16.h>
#include <hip/hip_fp16.h>

// 2-layer LSTM, B=32 T=512 F=1024. MFMA f16 core, latency-optimized step.
// 256 WGs x 256 thr (1 WG/CU). WG owns 16 cols of [Wi;Wh] (f16 LDS, B-frag order).
// Waves 0,1: h-part — h(t) read DIRECTLY from global (sc0sc1) as A-fragments,
// 4x8-load pipelined with counted vmcnt. Waves 2,3: x-part (L2-cached fp32+cvt).
// Cross-wave K-reduce via padded LDS; gates on 64 threads (c-state in regs);
// h ring = packed-f16 write-through stores; distributed-flag grid barrier with
// BATCHED 4-flag poll (one fabric round trip per iteration).

typedef _Float16 f16x8 __attribute__((ext_vector_type(8)));
typedef __fp16 fp16x2 __attribute__((ext_vector_type(2)));
typedef float f32x4 __attribute__((ext_vector_type(4)));

#define NB 32
#define NTT 512
#define NF 1024
#define NG 4096
#define TFE (NTT * NF)
#define NWG 256
#define NTHR 256

#define W_BYTES 65536                 // [64 s][64 lane][8 f16]
#define ZSEG 272                      // 16 rows * 17 (pad)
#define Z_FLOATS (8 * ZSEG)
#define LDS_BYTES (W_BYTES + Z_FLOATS * 4)   // 74240

__device__ __forceinline__ float sigm(float v) { return 1.0f / (1.0f + __expf(-v)); }
__device__ __forceinline__ float tanh_s(float v) {
  float a = fabsf(v);
  float e = __expf(-2.0f * a);
  float t = (1.0f - e) / (1.0f + e);
  return v < 0.0f ? -t : t;
}

__device__ __forceinline__ unsigned pk(float a, float b) {
  union { fp16x2 h2; unsigned u; } c;
  c.h2 = __builtin_amdgcn_cvt_pkrtz(a, b);
  return c.u;
}

__device__ __forceinline__ f16x8 cvt8(f32x4 lo, f32x4 hi) {
  union { unsigned u[4]; f16x8 h8; } u;
  u.u[0] = pk(lo[0], lo[1]);
  u.u[1] = pk(lo[2], lo[3]);
  u.u[2] = pk(hi[0], hi[1]);
  u.u[3] = pk(hi[2], hi[3]);
  return u.h8;
}

// 4 coherent 16B loads from p + {0,64,128,192} (one K-batch of A-fragments)
__device__ __forceinline__ void ld4(f16x8 o[4], const char* p) {
  asm volatile("global_load_dwordx4 %0, %4, off sc0 sc1\n\t"
               "global_load_dwordx4 %1, %4, off offset:64 sc0 sc1\n\t"
               "global_load_dwordx4 %2, %4, off offset:128 sc0 sc1\n\t"
               "global_load_dwordx4 %3, %4, off offset:192 sc0 sc1"
               : "=v"(o[0]), "=v"(o[1]), "=v"(o[2]), "=v"(o[3])
               : "v"(p) : "memory");
}

__global__ __launch_bounds__(NTHR, 1) void lstm_persist(
    const float* __restrict__ x,
    const float* __restrict__ Wi0, const float* __restrict__ Wh0, const float* __restrict__ bv0,
    const float* __restrict__ Wi1, const float* __restrict__ Wh1, const float* __restrict__ bv1,
    float* __restrict__ out, unsigned short* __restrict__ hring_u16,
    unsigned* __restrict__ bar) {
  extern __shared__ char lds[];
  f16x8* Wl = (f16x8*)lds;                 // Wl[s*64 + lane]
  float* Zr = (float*)(lds + W_BYTES);     // Zr[(w*2+mt)*ZSEG + row*17 + n]

  const int wg = blockIdx.x;
  const int tid = threadIdx.x;
  const int w = tid >> 6;          // waves 0,1: h-part; waves 2,3: x-part
  const int lane = tid & 63;
  const int r = lane & 15;         // fragment row index
  const int g = lane >> 4;         // k-group
  unsigned gen = 0;

  auto gridbar = [&]() {
    asm volatile("s_waitcnt vmcnt(0) lgkmcnt(0)" ::: "memory");
    __syncthreads();
    ++gen;
    if (tid < 64) {
      if (tid == 0)
        asm volatile("global_store_dword %0, %1, off sc0 sc1"
                     :: "v"(&bar[wg]), "v"(gen) : "memory");
      for (;;) {
        unsigned v0, v1, v2, v3;
        asm volatile("global_load_dword %0, %4, off sc0 sc1\n\t"
                     "global_load_dword %1, %5, off sc0 sc1\n\t"
                     "global_load_dword %2, %6, off sc0 sc1\n\t"
                     "global_load_dword %3, %7, off sc0 sc1\n\t"
                     "s_waitcnt vmcnt(0)"
                     : "=v"(v0), "=v"(v1), "=v"(v2), "=v"(v3)
                     : "v"(&bar[tid]), "v"(&bar[tid + 64]),
                       "v"(&bar[tid + 128]), "v"(&bar[tid + 192])
                     : "memory");
        if (__all((v0 >= gen) & (v1 >= gen) & (v2 >= gen) & (v3 >= gen))) break;
        __builtin_amdgcn_s_sleep(1);
      }
    }
    __syncthreads();
  };

  for (int layer = 0; layer < 2; ++layer) {
    const float* Wi = layer ? Wi1 : Wi0;
    const float* Wh = layer ? Wh1 : Wh0;
    const float* bv = layer ? bv1 : bv0;
    const float* xsrc = layer ? out : x;   // layer-1 input = y0 (fp32, in d_out)
    unsigned* hu = (unsigned*)(hring_u16 + (size_t)layer * 2 * NB * NF); // packed f16

    if (layer == 1) {
      // y0 handoff across XCDs: wbl2 flush, barrier, inv (2 full fences total)
      __threadfence();
      gridbar();
      __threadfence();
    }
    __syncthreads();  // prior Wl readers done — safe to overwrite

    // ---- stage W slice -> f16 LDS in B-fragment order ----
    // k -> (s=k>>5, kg=(k>>3)&3, jj=k&7); col n=q*4+j -> lane L=kg*16+n
    for (int idx = tid; idx < 8192; idx += NTHR) {
      const int k = idx >> 2, q = idx & 3;
      const float* src = (k < NF) ? (Wi + (size_t)k * NG) : (Wh + (size_t)(k - NF) * NG);
      const f32x4 v = *(const f32x4*)(src + q * NF + wg * 4);
      const int s = k >> 5, kg = (k >> 3) & 3, jj = k & 7;
#pragma unroll
      for (int j = 0; j < 4; ++j) {
        _Float16* dst = (_Float16*)&Wl[(s * 64) + (kg * 16) + (q * 4 + j)];
        dst[jj] = (_Float16)v[j];
      }
    }
    // zero h ring phase 0 (write-through, matching the bypass-read protocol)
    if (tid < 64) {
      const int b = tid >> 1, jp2 = tid & 1;
      __hip_atomic_store(&hu[b * 512 + wg * 2 + jp2], 0u,
                         __ATOMIC_RELAXED, __HIP_MEMORY_SCOPE_AGENT);
    }
    float bias[4][2];
    if (tid < 64) {
      const int jp2 = tid & 1;
#pragma unroll
      for (int q = 0; q < 4; ++q) {
        bias[q][0] = bv[q * NF + wg * 4 + 2 * jp2];
        bias[q][1] = bv[q * NF + wg * 4 + 2 * jp2 + 1];
      }
    }
    float cst[2] = {0.f, 0.f};
    float2 y_prev = {0.f, 0.f};
    __syncthreads();
    gridbar();  // W staged + h zeroed everywhere

    for (int t = 0; t < NTT; ++t) {
      f32x4 acc0 = {0.f, 0.f, 0.f, 0.f}, acc1 = {0.f, 0.f, 0.f, 0.f};

      if (w < 2) {
        // ---- h-part: direct A-fragment loads, 4 batches x 8, 2 in flight ----
        // lane(g,r) tile m: h[b = m*16+r][k = w*512 + ks*32 + g*8 .. +7]
        const char* hb = (const char*)hu + (size_t)(t & 1) * NB * NF * 2;
        const char* p0 = hb + r * 2048 + w * 1024 + g * 16;
        const char* p1 = p0 + 16 * 2048;
        f16x8 Ta0[4], Tb0[4], Ta1[4], Tb1[4], Ta2[4], Tb2[4], Ta3[4], Tb3[4];
        ld4(Ta0, p0);        ld4(Tb0, p1);          // batch0   (vm 8)
        ld4(Ta1, p0 + 256);  ld4(Tb1, p1 + 256);    // batch1   (vm 16)
        asm volatile("s_waitcnt vmcnt(8)" ::: "memory");   // batch0 ready
        __builtin_amdgcn_sched_barrier(0);
        ld4(Ta2, p0 + 512);  ld4(Tb2, p1 + 512);    // batch2   (vm 16)
#pragma unroll
        for (int kk = 0; kk < 4; ++kk) {
          const f16x8 B = Wl[(32 + w * 16 + kk) * 64 + lane];
          acc0 = __builtin_amdgcn_mfma_f32_16x16x32_f16(Ta0[kk], B, acc0, 0, 0, 0);
          acc1 = __builtin_amdgcn_mfma_f32_16x16x32_f16(Tb0[kk], B, acc1, 0, 0, 0);
        }
        asm volatile("s_waitcnt vmcnt(8)" ::: "memory");   // batch1 ready
        __builtin_amdgcn_sched_barrier(0);
        ld4(Ta3, p0 + 768);  ld4(Tb3, p1 + 768);    // batch3   (vm 16)
#pragma unroll
        for (int kk = 0; kk < 4; ++kk) {
          const f16x8 B = Wl[(32 + w * 16 + 4 + kk) * 64 + lane];
          acc0 = __builtin_amdgcn_mfma_f32_16x16x32_f16(Ta1[kk], B, acc0, 0, 0, 0);
          acc1 = __builtin_amdgcn_mfma_f32_16x16x32_f16(Tb1[kk], B, acc1, 0, 0, 0);
        }
        asm volatile("s_waitcnt vmcnt(8)" ::: "memory");   // batch2 ready
        __builtin_amdgcn_sched_barrier(0);
#pragma unroll
        for (int kk = 0; kk < 4; ++kk) {
          const f16x8 B = Wl[(32 + w * 16 + 8 + kk) * 64 + lane];
          acc0 = __builtin_amdgcn_mfma_f32_16x16x32_f16(Ta2[kk], B, acc0, 0, 0, 0);
          acc1 = __builtin_amdgcn_mfma_f32_16x16x32_f16(Tb2[kk], B, acc1, 0, 0, 0);
        }
        asm volatile("s_waitcnt vmcnt(0)" ::: "memory");   // batch3 ready
        __builtin_amdgcn_sched_barrier(0);
#pragma unroll
        for (int kk = 0; kk < 4; ++kk) {
          const f16x8 B = Wl[(32 + w * 16 + 12 + kk) * 64 + lane];
          acc0 = __builtin_amdgcn_mfma_f32_16x16x32_f16(Ta3[kk], B, acc0, 0, 0, 0);
          acc1 = __builtin_amdgcn_mfma_f32_16x16x32_f16(Tb3[kk], B, acc1, 0, 0, 0);
        }
      } else {
        // ---- x-part: L2-cached fp32 loads + cvt (off critical path) ----
        const float* p0 = xsrc + (size_t)r * TFE + (size_t)t * NF + (w - 2) * 512 + g * 8;
        const float* p1 = p0 + (size_t)16 * TFE;
#pragma unroll
        for (int ks = 0; ks < 16; ++ks) {
          const f16x8 B = Wl[((w - 2) * 16 + ks) * 64 + lane];
          const f32x4 a0l = *(const f32x4*)(p0 + ks * 32);
          const f32x4 a0h = *(const f32x4*)(p0 + ks * 32 + 4);
          const f32x4 a1l = *(const f32x4*)(p1 + ks * 32);
          const f32x4 a1h = *(const f32x4*)(p1 + ks * 32 + 4);
          acc0 = __builtin_amdgcn_mfma_f32_16x16x32_f16(cvt8(a0l, a0h), B, acc0, 0, 0, 0);
          acc1 = __builtin_amdgcn_mfma_f32_16x16x32_f16(cvt8(a1l, a1h), B, acc1, 0, 0, 0);
        }
      }

      // ---- cross-wave K reduction via LDS ----
      // C/D layout: col n = lane&15, row = (lane>>4)*4 + reg
      {
        float* zb0 = Zr + (w * 2 + 0) * ZSEG;
        float* zb1 = Zr + (w * 2 + 1) * ZSEG;
#pragma unroll
        for (int reg = 0; reg < 4; ++reg) {
          zb0[(g * 4 + reg) * 17 + r] = acc0[reg];
          zb1[(g * 4 + reg) * 17 + r] = acc1[reg];
        }
      }
      __syncthreads();

      // ---- gates: 64 threads, 2 feats each; c-state in regs ----
      if (tid < 64) {
        const int b = tid >> 1, jp2 = tid & 1;
        const int mt = b >> 4, row = b & 15;
        float hv[2];
#pragma unroll
        for (int e = 0; e < 2; ++e) {
          float zq[4];
#pragma unroll
          for (int q = 0; q < 4; ++q) {
            const int n = q * 4 + 2 * jp2 + e;
            float sum = bias[q][e];
#pragma unroll
            for (int ww = 0; ww < 4; ++ww)
              sum += Zr[(ww * 2 + mt) * ZSEG + row * 17 + n];
            zq[q] = sum;
          }
          const float cn = sigm(zq[1]) * cst[e] + sigm(zq[0]) * tanh_s(zq[2]);
          hv[e] = sigm(zq[3]) * tanh_s(cn);
          cst[e] = cn;
        }
        // h ring: packed f16 write-through store
        __hip_atomic_store(&hu[((t + 1) & 1) * NB * 512 + b * 512 + wg * 2 + jp2],
                           pk(hv[0], hv[1]), __ATOMIC_RELAXED, __HIP_MEMORY_SCOPE_AGENT);
        // outputs (fp32)
        float* orow = out + (size_t)b * TFE + (size_t)wg * 4 + 2 * jp2;
        if (layer == 0) {
          *(float2*)(orow + (size_t)t * NF) = make_float2(hv[0], hv[1]);
        } else {
          if (t > 0) *(float2*)(orow + (size_t)(t - 1) * NF) = y_prev;
          y_prev = make_float2(hv[0], hv[1]);
        }
      }
      gridbar();  // h(t+1) drained to coherence point before next step reads
    }
    if (layer == 1 && tid < 64) {
      const int b = tid >> 1, jp2 = tid & 1;
      *(float2*)(out + (size_t)b * TFE + (size_t)(NTT - 1) * NF + wg * 4 + 2 * jp2) = y_prev;
    }
  }
}

extern "C" void kernel_launch(void* const* d_in, const int* in_sizes, int n_in,
                              void* d_out, int out_size, void* d_ws, size_t ws_size,
                              hipStream_t stream) {
  (void)in_sizes; (void)n_in; (void)out_size; (void)ws_size;
  const float* x   = (const float*)d_in[0];
  const float* Wi0 = (const float*)d_in[1];
  const float* Wh0 = (const float*)d_in[2];
  const float* b0  = (const float*)d_in[3];
  const float* Wi1 = (const float*)d_in[4];
  const float* Wh1 = (const float*)d_in[5];
  const float* b1  = (const float*)d_in[6];
  float* out = (float*)d_out;

  unsigned short* hring = (unsigned short*)d_ws;   // [2 layers][2 phases][32][1024] f16
  unsigned* bar = (unsigned*)((char*)d_ws + (size_t)2 * 2 * NB * NF * 2);  // +256KB

  (void)hipMemsetAsync(bar, 0, 4096, stream);  // flag array reset (replay-safe)

  (void)hipFuncSetAttribute((const void*)lstm_persist,
                            hipFuncAttributeMaxDynamicSharedMemorySize, LDS_BYTES);

  lstm_persist<<<dim3(NWG), dim3(NTHR), LDS_BYTES, stream>>>(
      x, Wi0, Wh0, b0, Wi1, Wh1, b1, out, hring, bar);
}

// Round 8
// 6185.369 us; speedup vs baseline: 10.5223x; 1.8015x over previous
//
#include <hip/hip_runtime.h>
#include <hip/hip_bf16.h>
#include <hip/hip_fp16.h>

// 2-layer LSTM, B=32 T=512 F=1024. MFMA f16, LAYER-PIPELINED persistent kernel.
// 256 WGs x 512 thr (1 WG/CU, 8 waves). WGs 0-127 = layer 0 (step t=rd),
// WGs 128-255 = layer 1 (step t=rd-1) in the SAME barrier round: 513 rounds
// instead of 1026. Each WG owns 32 cols of [Wi;Wh] (8 feats x 4 gates),
// W = f16 LDS 128KB in B-frag order. 8 waves = 4 K-quarters x 2 M-tiles.
// L0: Kq0,1 = x (fp32 cached), Kq2,3 = h0 ring (f16 sc0sc1 direct A-frags).
// L1: Kq0,1 = y0 = h0 ring, Kq2,3 = h1 ring (all f16 coherent loads).
// out written ONLY by L1. Distributed-flag grid barrier.
// R8 fix: EARLY-CLOBBER (=&v) on all multi-load asm outputs — R7's plain =v
// let regalloc alias an output with a later load's address pair -> fault.

typedef _Float16 f16x8 __attribute__((ext_vector_type(8)));
typedef __fp16 fp16x2 __attribute__((ext_vector_type(2)));
typedef float f32x4 __attribute__((ext_vector_type(4)));

#define NB 32
#define NTT 512
#define NF 1024
#define NG 4096
#define TFE (NTT * NF)
#define NWG 256
#define NTHR 512

#define W_F16X8 8192                    // [64 s][2 ntile][64 lane] f16x8
#define W_BYTES (W_F16X8 * 16)          // 131072
#define ZQSEG 33                        // 32 cols + 1 pad
#define Z_FLOATS (8 * 16 * ZQSEG)       // waves x rows x cols
#define LDS_BYTES (W_BYTES + Z_FLOATS * 4)   // 147968
#define RINGB 65536                     // one h phase: 32 b x 1024 f16

__device__ __forceinline__ float sigm(float v) { return 1.0f / (1.0f + __expf(-v)); }
__device__ __forceinline__ float tanh_s(float v) {
  float a = fabsf(v);
  float e = __expf(-2.0f * a);
  float t = (1.0f - e) / (1.0f + e);
  return v < 0.0f ? -t : t;
}

__device__ __forceinline__ unsigned pk(float a, float b) {
  union { fp16x2 h2; unsigned u; } c;
  c.h2 = __builtin_amdgcn_cvt_pkrtz(a, b);
  return c.u;
}

__device__ __forceinline__ f16x8 cvt8(f32x4 lo, f32x4 hi) {
  union { unsigned u[4]; f16x8 h8; } u;
  u.u[0] = pk(lo[0], lo[1]);
  u.u[1] = pk(lo[2], lo[3]);
  u.u[2] = pk(hi[0], hi[1]);
  u.u[3] = pk(hi[2], hi[3]);
  return u.h8;
}

// 4 coherent 16B loads from p + {0,64,128,192}: one K-batch (4 ks) of A-frags.
// "=&v" early-clobber: outputs must NOT alias the address pair %4.
__device__ __forceinline__ void ld4(f16x8 o[4], const char* p) {
  asm volatile("global_load_dwordx4 %0, %4, off sc0 sc1\n\t"
               "global_load_dwordx4 %1, %4, off offset:64 sc0 sc1\n\t"
               "global_load_dwordx4 %2, %4, off offset:128 sc0 sc1\n\t"
               "global_load_dwordx4 %3, %4, off offset:192 sc0 sc1"
               : "=&v"(o[0]), "=&v"(o[1]), "=&v"(o[2]), "=&v"(o[3])
               : "v"(p) : "memory");
}

__global__ __launch_bounds__(NTHR, 1) void lstm_persist(
    const float* __restrict__ x,
    const float* __restrict__ Wi0, const float* __restrict__ Wh0, const float* __restrict__ bv0,
    const float* __restrict__ Wi1, const float* __restrict__ Wh1, const float* __restrict__ bv1,
    float* __restrict__ out, unsigned short* __restrict__ hring_u16,
    unsigned* __restrict__ bar) {
  extern __shared__ char lds[];
  f16x8* Wl = (f16x8*)lds;                 // Wl[(s*2+ntile)*64 + lane]
  float* Zr = (float*)(lds + W_BYTES);     // Zr[(w*16+row)*33 + col]

  const int wg = blockIdx.x;
  const int tid = threadIdx.x;
  const int role = wg >> 7;        // 0: layer 0, 1: layer 1
  const int fg = wg & 127;         // feature group: feats fg*8 .. +7
  const int fbase = fg * 8;
  const int w = tid >> 6;          // wave 0..7
  const int Kq = w >> 1;           // K-quarter (512 k each)
  const int mt = w & 1;            // M-tile (16 batches each)
  const int lane = tid & 63;
  const int lr = lane & 15;        // fragment row
  const int g = lane >> 4;         // k-group
  unsigned gen = 0;

  auto gridbar = [&]() {
    asm volatile("s_waitcnt vmcnt(0) lgkmcnt(0)" ::: "memory");
    __syncthreads();
    ++gen;
    if (tid < 64) {
      if (tid == 0)
        asm volatile("global_store_dword %0, %1, off sc0 sc1"
                     :: "v"(&bar[wg]), "v"(gen) : "memory");
      for (;;) {
        unsigned v0, v1, v2, v3;
        asm volatile("global_load_dword %0, %4, off sc0 sc1\n\t"
                     "global_load_dword %1, %5, off sc0 sc1\n\t"
                     "global_load_dword %2, %6, off sc0 sc1\n\t"
                     "global_load_dword %3, %7, off sc0 sc1\n\t"
                     "s_waitcnt vmcnt(0)"
                     : "=&v"(v0), "=&v"(v1), "=&v"(v2), "=&v"(v3)
                     : "v"(&bar[tid]), "v"(&bar[tid + 64]),
                       "v"(&bar[tid + 128]), "v"(&bar[tid + 192])
                     : "memory");
        if (__all((v0 >= gen) & (v1 >= gen) & (v2 >= gen) & (v3 >= gen))) break;
        __builtin_amdgcn_s_sleep(1);
      }
    }
    __syncthreads();
  };

  const float* Wi = role ? Wi1 : Wi0;
  const float* Wh = role ? Wh1 : Wh0;
  const float* bv = role ? bv1 : bv0;
  unsigned* h0 = (unsigned*)hring_u16;                       // layer-0 h ring (2 phases)
  unsigned* h1 = (unsigned*)(hring_u16 + 2 * NB * NF);       // layer-1 h ring
  unsigned* hmine = role ? h1 : h0;

  // ---- one-time W slice -> f16 LDS in B-fragment order ----
  // k -> (s=k>>5, kg=(k>>3)&3, jj=k&7); col c=q*8+f -> (ntile=c>>4, n=c&15)
  for (int idx = tid; idx < 16384; idx += NTHR) {
    const int k = idx >> 3, chunk = idx & 7;
    const int q = chunk >> 1, half = chunk & 1;
    const float* src = (k < NF) ? (Wi + (size_t)k * NG) : (Wh + (size_t)(k - NF) * NG);
    const f32x4 v = *(const f32x4*)(src + q * NF + fbase + half * 4);
    const int s = k >> 5, kg = (k >> 3) & 3, jj = k & 7;
#pragma unroll
    for (int j = 0; j < 4; ++j) {
      const int c = q * 8 + half * 4 + j;
      _Float16* dst = (_Float16*)&Wl[((s * 2 + (c >> 4)) * 64) + kg * 16 + (c & 15)];
      dst[jj] = (_Float16)v[j];
    }
  }
  // zero own ring phase 0 (write-through, matches bypass-read protocol)
  if (tid < 128) {
    const int b = tid >> 2, fp = tid & 3;
    __hip_atomic_store(&hmine[b * 512 + (fbase >> 1) + fp], 0u,
                       __ATOMIC_RELAXED, __HIP_MEMORY_SCOPE_AGENT);
  }
  float bias[4][2];
  if (tid < 128) {
    const int fp = tid & 3;
#pragma unroll
    for (int q = 0; q < 4; ++q) {
      bias[q][0] = bv[q * NF + fbase + 2 * fp];
      bias[q][1] = bv[q * NF + fbase + 2 * fp + 1];
    }
  }
  float cst[2] = {0.f, 0.f};
  __syncthreads();
  gridbar();  // W staged + rings zeroed everywhere

  for (int rd = 0; rd <= NTT; ++rd) {
    const bool doit = role == 0 ? (rd < NTT) : (rd >= 1);
    const int t = role == 0 ? rd : rd - 1;

    if (doit) {
      f32x4 acc0 = {0.f, 0.f, 0.f, 0.f}, acc1 = {0.f, 0.f, 0.f, 0.f};
      const int brow = mt * 16 + lr;

      bool f16src;
      const char* hp = nullptr;
      const float* xp = nullptr;
      if (role == 0) {
        if (Kq < 2) {
          xp = x + (size_t)brow * TFE + (size_t)t * NF + Kq * 512 + g * 8;
          f16src = false;
        } else {
          hp = (const char*)h0 + (size_t)(rd & 1) * RINGB + brow * 2048
               + ((Kq - 2) * 512 + g * 8) * 2;
          f16src = true;
        }
      } else {
        if (Kq < 2)
          hp = (const char*)h0 + (size_t)(rd & 1) * RINGB + brow * 2048
               + (Kq * 512 + g * 8) * 2;        // y0(t) = h0 ring
        else
          hp = (const char*)h1 + (size_t)((rd - 1) & 1) * RINGB + brow * 2048
               + ((Kq - 2) * 512 + g * 8) * 2;
        f16src = true;
      }

      if (f16src) {
        // 4 batches x 4 ks, 2 batches of loads in flight
        f16x8 T0[4], T1[4], T2[4], T3[4];
        ld4(T0, hp); ld4(T1, hp + 256);
        asm volatile("s_waitcnt vmcnt(4)" ::: "memory");
        __builtin_amdgcn_sched_barrier(0);
        ld4(T2, hp + 512);
#pragma unroll
        for (int kk = 0; kk < 4; ++kk) {
          const int s = Kq * 16 + kk;
          acc0 = __builtin_amdgcn_mfma_f32_16x16x32_f16(T0[kk], Wl[(s * 2 + 0) * 64 + lane], acc0, 0, 0, 0);
          acc1 = __builtin_amdgcn_mfma_f32_16x16x32_f16(T0[kk], Wl[(s * 2 + 1) * 64 + lane], acc1, 0, 0, 0);
        }
        asm volatile("s_waitcnt vmcnt(4)" ::: "memory");
        __builtin_amdgcn_sched_barrier(0);
        ld4(T3, hp + 768);
#pragma unroll
        for (int kk = 0; kk < 4; ++kk) {
          const int s = Kq * 16 + 4 + kk;
          acc0 = __builtin_amdgcn_mfma_f32_16x16x32_f16(T1[kk], Wl[(s * 2 + 0) * 64 + lane], acc0, 0, 0, 0);
          acc1 = __builtin_amdgcn_mfma_f32_16x16x32_f16(T1[kk], Wl[(s * 2 + 1) * 64 + lane], acc1, 0, 0, 0);
        }
        asm volatile("s_waitcnt vmcnt(4)" ::: "memory");
        __builtin_amdgcn_sched_barrier(0);
#pragma unroll
        for (int kk = 0; kk < 4; ++kk) {
          const int s = Kq * 16 + 8 + kk;
          acc0 = __builtin_amdgcn_mfma_f32_16x16x32_f16(T2[kk], Wl[(s * 2 + 0) * 64 + lane], acc0, 0, 0, 0);
          acc1 = __builtin_amdgcn_mfma_f32_16x16x32_f16(T2[kk], Wl[(s * 2 + 1) * 64 + lane], acc1, 0, 0, 0);
        }
        asm volatile("s_waitcnt vmcnt(0)" ::: "memory");
        __builtin_amdgcn_sched_barrier(0);
#pragma unroll
        for (int kk = 0; kk < 4; ++kk) {
          const int s = Kq * 16 + 12 + kk;
          acc0 = __builtin_amdgcn_mfma_f32_16x16x32_f16(T3[kk], Wl[(s * 2 + 0) * 64 + lane], acc0, 0, 0, 0);
          acc1 = __builtin_amdgcn_mfma_f32_16x16x32_f16(T3[kk], Wl[(s * 2 + 1) * 64 + lane], acc1, 0, 0, 0);
        }
      } else {
#pragma unroll
        for (int ks = 0; ks < 16; ++ks) {
          const int s = Kq * 16 + ks;
          const f32x4 al = *(const f32x4*)(xp + ks * 32);
          const f32x4 ah = *(const f32x4*)(xp + ks * 32 + 4);
          const f16x8 A = cvt8(al, ah);
          acc0 = __builtin_amdgcn_mfma_f32_16x16x32_f16(A, Wl[(s * 2 + 0) * 64 + lane], acc0, 0, 0, 0);
          acc1 = __builtin_amdgcn_mfma_f32_16x16x32_f16(A, Wl[(s * 2 + 1) * 64 + lane], acc1, 0, 0, 0);
        }
      }

      // cross-wave K reduce: C/D layout col n=lane&15, row=(lane>>4)*4+reg
      {
        float* zb = Zr + (size_t)w * 16 * ZQSEG;
#pragma unroll
        for (int reg = 0; reg < 4; ++reg) {
          zb[(g * 4 + reg) * ZQSEG + lr] = acc0[reg];
          zb[(g * 4 + reg) * ZQSEG + 16 + lr] = acc1[reg];
        }
      }
      __syncthreads();

      // gates: 128 threads, (b, feat-pair); c-state in regs
      if (tid < 128) {
        const int b = tid >> 2, fp = tid & 3;
        const int bmt = b >> 4, row = b & 15;
        float hv[2];
#pragma unroll
        for (int e = 0; e < 2; ++e) {
          const int f = 2 * fp + e;
          float zq[4];
#pragma unroll
          for (int q = 0; q < 4; ++q) {
            const int c = q * 8 + f;
            float sum = bias[q][e];
#pragma unroll
            for (int kq = 0; kq < 4; ++kq)
              sum += Zr[((kq * 2 + bmt) * 16 + row) * ZQSEG + c];
            zq[q] = sum;
          }
          const float cn = sigm(zq[1]) * cst[e] + sigm(zq[0]) * tanh_s(zq[2]);
          hv[e] = sigm(zq[3]) * tanh_s(cn);
          cst[e] = cn;
        }
        // own h ring: L0 writes phase (rd+1)&1, L1 writes phase rd&1
        const int wph = role == 0 ? ((rd + 1) & 1) : (rd & 1);
        __hip_atomic_store(&hmine[wph * NB * 512 + b * 512 + (fbase >> 1) + fp],
                           pk(hv[0], hv[1]), __ATOMIC_RELAXED, __HIP_MEMORY_SCOPE_AGENT);
        if (role == 1)   // final output: only L1 writes out
          *(float2*)(out + (size_t)b * TFE + (size_t)t * NF + fbase + 2 * fp) =
              make_float2(hv[0], hv[1]);
      }
    }
    gridbar();  // ring stores drained before next round's reads
  }
}

extern "C" void kernel_launch(void* const* d_in, const int* in_sizes, int n_in,
                              void* d_out, int out_size, void* d_ws, size_t ws_size,
                              hipStream_t stream) {
  (void)in_sizes; (void)n_in; (void)out_size; (void)ws_size;
  const float* x   = (const float*)d_in[0];
  const float* Wi0 = (const float*)d_in[1];
  const float* Wh0 = (const float*)d_in[2];
  const float* b0  = (const float*)d_in[3];
  const float* Wi1 = (const float*)d_in[4];
  const float* Wh1 = (const float*)d_in[5];
  const float* b1  = (const float*)d_in[6];
  float* out = (float*)d_out;

  unsigned short* hring = (unsigned short*)d_ws;   // h0 ring 128KB + h1 ring 128KB
  unsigned* bar = (unsigned*)((char*)d_ws + 262144);

  (void)hipMemsetAsync(bar, 0, 4096, stream);  // flag array reset (replay-safe)

  (void)hipFuncSetAttribute((const void*)lstm_persist,
                            hipFuncAttributeMaxDynamicSharedMemorySize, LDS_BYTES);

  lstm_persist<<<dim3(NWG), dim3(NTHR), LDS_BYTES, stream>>>(
      x, Wi0, Wh0, b0, Wi1, Wh1, b1, out, hring, bar);
}

// Round 9
// 4238.728 us; speedup vs baseline: 15.3547x; 1.4593x over previous
//
#include <hip/hip_runtime.h>
#include <hip/hip_bf16.h>
#include <hip/hip_fp16.h>

// 2-layer LSTM, B=32 T=512 F=1024. MFMA f16, LAYER-PIPELINED persistent kernel.
// 256 WGs x 512 thr (1 WG/CU, 8 waves). WGs 0-127 = layer 0 (step t=rd),
// WGs 128-255 = layer 1 (step t=rd-1): 513 rounds. W = f16 LDS (B-frag order).
// h exchanged via sc0sc1 write-through rings (no L2 maintenance).
// R9: CONTENTION-FREE barrier — 64B-spaced producer flags, ONE master WG polls
// (1 poller per line), then fans out to 256 per-WG 64B-spaced mailboxes
// (1 spinner per line). Replaces all-WGs-poll-16-shared-lines (LLC serialization).

typedef _Float16 f16x8 __attribute__((ext_vector_type(8)));
typedef __fp16 fp16x2 __attribute__((ext_vector_type(2)));
typedef float f32x4 __attribute__((ext_vector_type(4)));

#define NB 32
#define NTT 512
#define NF 1024
#define NG 4096
#define TFE (NTT * NF)
#define NWG 256
#define NTHR 512

#define W_F16X8 8192                    // [64 s][2 ntile][64 lane] f16x8
#define W_BYTES (W_F16X8 * 16)          // 131072
#define ZQSEG 33                        // 32 cols + 1 pad
#define Z_FLOATS (8 * 16 * ZQSEG)
#define LDS_BYTES (W_BYTES + Z_FLOATS * 4)   // 147968
#define RINGB 65536                     // one h phase: 32 b x 1024 f16
#define MBOX 4096                       // u32 index of mailbox region (16KB in)

__device__ __forceinline__ float sigm(float v) { return 1.0f / (1.0f + __expf(-v)); }
__device__ __forceinline__ float tanh_s(float v) {
  float a = fabsf(v);
  float e = __expf(-2.0f * a);
  float t = (1.0f - e) / (1.0f + e);
  return v < 0.0f ? -t : t;
}

__device__ __forceinline__ unsigned pk(float a, float b) {
  union { fp16x2 h2; unsigned u; } c;
  c.h2 = __builtin_amdgcn_cvt_pkrtz(a, b);
  return c.u;
}

__device__ __forceinline__ f16x8 cvt8(f32x4 lo, f32x4 hi) {
  union { unsigned u[4]; f16x8 h8; } u;
  u.u[0] = pk(lo[0], lo[1]);
  u.u[1] = pk(lo[2], lo[3]);
  u.u[2] = pk(hi[0], hi[1]);
  u.u[3] = pk(hi[2], hi[3]);
  return u.h8;
}

__device__ __forceinline__ unsigned ldu(const unsigned* p) {
  unsigned v;
  asm volatile("global_load_dword %0, %1, off sc0 sc1\n\ts_waitcnt vmcnt(0)"
               : "=&v"(v) : "v"(p) : "memory");
  return v;
}

// 4 coherent 16B loads from p + {0,64,128,192}; "=&v": no alias with addr %4.
__device__ __forceinline__ void ld4(f16x8 o[4], const char* p) {
  asm volatile("global_load_dwordx4 %0, %4, off sc0 sc1\n\t"
               "global_load_dwordx4 %1, %4, off offset:64 sc0 sc1\n\t"
               "global_load_dwordx4 %2, %4, off offset:128 sc0 sc1\n\t"
               "global_load_dwordx4 %3, %4, off offset:192 sc0 sc1"
               : "=&v"(o[0]), "=&v"(o[1]), "=&v"(o[2]), "=&v"(o[3])
               : "v"(p) : "memory");
}

__global__ __launch_bounds__(NTHR, 1) void lstm_persist(
    const float* __restrict__ x,
    const float* __restrict__ Wi0, const float* __restrict__ Wh0, const float* __restrict__ bv0,
    const float* __restrict__ Wi1, const float* __restrict__ Wh1, const float* __restrict__ bv1,
    float* __restrict__ out, unsigned short* __restrict__ hring_u16,
    unsigned* __restrict__ bar) {
  extern __shared__ char lds[];
  f16x8* Wl = (f16x8*)lds;                 // Wl[(s*2+ntile)*64 + lane]
  float* Zr = (float*)(lds + W_BYTES);     // Zr[(w*16+row)*33 + col]

  const int wg = blockIdx.x;
  const int tid = threadIdx.x;
  const int role = wg >> 7;        // 0: layer 0, 1: layer 1
  const int fg = wg & 127;         // feature group: feats fg*8 .. +7
  const int fbase = fg * 8;
  const int w = tid >> 6;          // wave 0..7
  const int Kq = w >> 1;           // K-quarter (512 k each)
  const int mt = w & 1;            // M-tile (16 batches each)
  const int lane = tid & 63;
  const int lr = lane & 15;        // fragment row
  const int g = lane >> 4;         // k-group
  unsigned gen = 0;

  // Contention-free grid barrier: flag[wg] at bar[wg*16] (64B apart);
  // master (wg 0) polls all flags (1 lane per line), fans out to mailboxes
  // bar[MBOX + wg*16]; each WG spins on its own mailbox line only.
  auto gridbar = [&]() {
    asm volatile("s_waitcnt vmcnt(0) lgkmcnt(0)" ::: "memory");
    __syncthreads();
    ++gen;
    if (tid == 0)
      asm volatile("global_store_dword %0, %1, off sc0 sc1"
                   :: "v"(&bar[wg * 16]), "v"(gen) : "memory");
    if (wg == 0) {
      if (tid < 64) {
        const unsigned* f0 = &bar[(tid * 4 + 0) * 16];
        const unsigned* f1 = &bar[(tid * 4 + 1) * 16];
        const unsigned* f2 = &bar[(tid * 4 + 2) * 16];
        const unsigned* f3 = &bar[(tid * 4 + 3) * 16];
        for (;;) {
          unsigned v0, v1, v2, v3;
          asm volatile("global_load_dword %0, %4, off sc0 sc1\n\t"
                       "global_load_dword %1, %5, off sc0 sc1\n\t"
                       "global_load_dword %2, %6, off sc0 sc1\n\t"
                       "global_load_dword %3, %7, off sc0 sc1\n\t"
                       "s_waitcnt vmcnt(0)"
                       : "=&v"(v0), "=&v"(v1), "=&v"(v2), "=&v"(v3)
                       : "v"(f0), "v"(f1), "v"(f2), "v"(f3)
                       : "memory");
          if (__all((v0 >= gen) & (v1 >= gen) & (v2 >= gen) & (v3 >= gen))) break;
        }
      }
      __syncthreads();                 // poll done before fanout
      if (tid < 256)
        asm volatile("global_store_dword %0, %1, off sc0 sc1"
                     :: "v"(&bar[MBOX + tid * 16]), "v"(gen) : "memory");
      __syncthreads();
    } else {
      if (tid == 0) {
        const unsigned* mb = &bar[MBOX + wg * 16];
        while (ldu(mb) < gen) __builtin_amdgcn_s_sleep(1);
      }
      __syncthreads();
    }
  };

  const float* Wi = role ? Wi1 : Wi0;
  const float* Wh = role ? Wh1 : Wh0;
  const float* bv = role ? bv1 : bv0;
  unsigned* h0 = (unsigned*)hring_u16;                       // layer-0 h ring (2 phases)
  unsigned* h1 = (unsigned*)(hring_u16 + 2 * NB * NF);       // layer-1 h ring
  unsigned* hmine = role ? h1 : h0;

  // ---- one-time W slice -> f16 LDS in B-fragment order ----
  for (int idx = tid; idx < 16384; idx += NTHR) {
    const int k = idx >> 3, chunk = idx & 7;
    const int q = chunk >> 1, half = chunk & 1;
    const float* src = (k < NF) ? (Wi + (size_t)k * NG) : (Wh + (size_t)(k - NF) * NG);
    const f32x4 v = *(const f32x4*)(src + q * NF + fbase + half * 4);
    const int s = k >> 5, kg = (k >> 3) & 3, jj = k & 7;
#pragma unroll
    for (int j = 0; j < 4; ++j) {
      const int c = q * 8 + half * 4 + j;
      _Float16* dst = (_Float16*)&Wl[((s * 2 + (c >> 4)) * 64) + kg * 16 + (c & 15)];
      dst[jj] = (_Float16)v[j];
    }
  }
  // zero own ring phase 0
  if (tid < 128) {
    const int b = tid >> 2, fp = tid & 3;
    __hip_atomic_store(&hmine[b * 512 + (fbase >> 1) + fp], 0u,
                       __ATOMIC_RELAXED, __HIP_MEMORY_SCOPE_AGENT);
  }
  float bias[4][2];
  if (tid < 128) {
    const int fp = tid & 3;
#pragma unroll
    for (int q = 0; q < 4; ++q) {
      bias[q][0] = bv[q * NF + fbase + 2 * fp];
      bias[q][1] = bv[q * NF + fbase + 2 * fp + 1];
    }
  }
  float cst[2] = {0.f, 0.f};
  __syncthreads();
  gridbar();  // W staged + rings zeroed everywhere

  for (int rd = 0; rd <= NTT; ++rd) {
    const bool doit = role == 0 ? (rd < NTT) : (rd >= 1);
    const int t = role == 0 ? rd : rd - 1;

    if (doit) {
      f32x4 acc0 = {0.f, 0.f, 0.f, 0.f}, acc1 = {0.f, 0.f, 0.f, 0.f};
      const int brow = mt * 16 + lr;

      bool f16src;
      const char* hp = nullptr;
      const float* xp = nullptr;
      if (role == 0) {
        if (Kq < 2) {
          xp = x + (size_t)brow * TFE + (size_t)t * NF + Kq * 512 + g * 8;
          f16src = false;
        } else {
          hp = (const char*)h0 + (size_t)(rd & 1) * RINGB + brow * 2048
               + ((Kq - 2) * 512 + g * 8) * 2;
          f16src = true;
        }
      } else {
        if (Kq < 2)
          hp = (const char*)h0 + (size_t)(rd & 1) * RINGB + brow * 2048
               + (Kq * 512 + g * 8) * 2;        // y0(t) = h0 ring
        else
          hp = (const char*)h1 + (size_t)((rd - 1) & 1) * RINGB + brow * 2048
               + ((Kq - 2) * 512 + g * 8) * 2;
        f16src = true;
      }

      if (f16src) {
        f16x8 T0[4], T1[4], T2[4], T3[4];
        ld4(T0, hp); ld4(T1, hp + 256);
        asm volatile("s_waitcnt vmcnt(4)" ::: "memory");
        __builtin_amdgcn_sched_barrier(0);
        ld4(T2, hp + 512);
#pragma unroll
        for (int kk = 0; kk < 4; ++kk) {
          const int s = Kq * 16 + kk;
          acc0 = __builtin_amdgcn_mfma_f32_16x16x32_f16(T0[kk], Wl[(s * 2 + 0) * 64 + lane], acc0, 0, 0, 0);
          acc1 = __builtin_amdgcn_mfma_f32_16x16x32_f16(T0[kk], Wl[(s * 2 + 1) * 64 + lane], acc1, 0, 0, 0);
        }
        asm volatile("s_waitcnt vmcnt(4)" ::: "memory");
        __builtin_amdgcn_sched_barrier(0);
        ld4(T3, hp + 768);
#pragma unroll
        for (int kk = 0; kk < 4; ++kk) {
          const int s = Kq * 16 + 4 + kk;
          acc0 = __builtin_amdgcn_mfma_f32_16x16x32_f16(T1[kk], Wl[(s * 2 + 0) * 64 + lane], acc0, 0, 0, 0);
          acc1 = __builtin_amdgcn_mfma_f32_16x16x32_f16(T1[kk], Wl[(s * 2 + 1) * 64 + lane], acc1, 0, 0, 0);
        }
        asm volatile("s_waitcnt vmcnt(4)" ::: "memory");
        __builtin_amdgcn_sched_barrier(0);
#pragma unroll
        for (int kk = 0; kk < 4; ++kk) {
          const int s = Kq * 16 + 8 + kk;
          acc0 = __builtin_amdgcn_mfma_f32_16x16x32_f16(T2[kk], Wl[(s * 2 + 0) * 64 + lane], acc0, 0, 0, 0);
          acc1 = __builtin_amdgcn_mfma_f32_16x16x32_f16(T2[kk], Wl[(s * 2 + 1) * 64 + lane], acc1, 0, 0, 0);
        }
        asm volatile("s_waitcnt vmcnt(0)" ::: "memory");
        __builtin_amdgcn_sched_barrier(0);
#pragma unroll
        for (int kk = 0; kk < 4; ++kk) {
          const int s = Kq * 16 + 12 + kk;
          acc0 = __builtin_amdgcn_mfma_f32_16x16x32_f16(T3[kk], Wl[(s * 2 + 0) * 64 + lane], acc0, 0, 0, 0);
          acc1 = __builtin_amdgcn_mfma_f32_16x16x32_f16(T3[kk], Wl[(s * 2 + 1) * 64 + lane], acc1, 0, 0, 0);
        }
      } else {
#pragma unroll
        for (int ks = 0; ks < 16; ++ks) {
          const int s = Kq * 16 + ks;
          const f32x4 al = *(const f32x4*)(xp + ks * 32);
          const f32x4 ah = *(const f32x4*)(xp + ks * 32 + 4);
          const f16x8 A = cvt8(al, ah);
          acc0 = __builtin_amdgcn_mfma_f32_16x16x32_f16(A, Wl[(s * 2 + 0) * 64 + lane], acc0, 0, 0, 0);
          acc1 = __builtin_amdgcn_mfma_f32_16x16x32_f16(A, Wl[(s * 2 + 1) * 64 + lane], acc1, 0, 0, 0);
        }
      }

      // cross-wave K reduce: C/D layout col n=lane&15, row=(lane>>4)*4+reg
      {
        float* zb = Zr + (size_t)w * 16 * ZQSEG;
#pragma unroll
        for (int reg = 0; reg < 4; ++reg) {
          zb[(g * 4 + reg) * ZQSEG + lr] = acc0[reg];
          zb[(g * 4 + reg) * ZQSEG + 16 + lr] = acc1[reg];
        }
      }
      __syncthreads();

      // gates: 128 threads, (b, feat-pair); c-state in regs
      if (tid < 128) {
        const int b = tid >> 2, fp = tid & 3;
        const int bmt = b >> 4, row = b & 15;
        float hv[2];
#pragma unroll
        for (int e = 0; e < 2; ++e) {
          const int f = 2 * fp + e;
          float zq[4];
#pragma unroll
          for (int q = 0; q < 4; ++q) {
            const int c = q * 8 + f;
            float sum = bias[q][e];
#pragma unroll
            for (int kq = 0; kq < 4; ++kq)
              sum += Zr[((kq * 2 + bmt) * 16 + row) * ZQSEG + c];
            zq[q] = sum;
          }
          const float cn = sigm(zq[1]) * cst[e] + sigm(zq[0]) * tanh_s(zq[2]);
          hv[e] = sigm(zq[3]) * tanh_s(cn);
          cst[e] = cn;
        }
        const int wph = role == 0 ? ((rd + 1) & 1) : (rd & 1);
        __hip_atomic_store(&hmine[wph * NB * 512 + b * 512 + (fbase >> 1) + fp],
                           pk(hv[0], hv[1]), __ATOMIC_RELAXED, __HIP_MEMORY_SCOPE_AGENT);
        if (role == 1)
          *(float2*)(out + (size_t)b * TFE + (size_t)t * NF + fbase + 2 * fp) =
              make_float2(hv[0], hv[1]);
      }
    }
    gridbar();  // ring stores drained before next round's reads
  }
}

extern "C" void kernel_launch(void* const* d_in, const int* in_sizes, int n_in,
                              void* d_out, int out_size, void* d_ws, size_t ws_size,
                              hipStream_t stream) {
  (void)in_sizes; (void)n_in; (void)out_size; (void)ws_size;
  const float* x   = (const float*)d_in[0];
  const float* Wi0 = (const float*)d_in[1];
  const float* Wh0 = (const float*)d_in[2];
  const float* b0  = (const float*)d_in[3];
  const float* Wi1 = (const float*)d_in[4];
  const float* Wh1 = (const float*)d_in[5];
  const float* b1  = (const float*)d_in[6];
  float* out = (float*)d_out;

  unsigned short* hring = (unsigned short*)d_ws;   // h0 ring 128KB + h1 ring 128KB
  unsigned* bar = (unsigned*)((char*)d_ws + 262144);  // flags 16KB + mailboxes 16KB

  (void)hipMemsetAsync(bar, 0, 32768, stream);  // flags+mailboxes reset (replay-safe)

  (void)hipFuncSetAttribute((const void*)lstm_persist,
                            hipFuncAttributeMaxDynamicSharedMemorySize, LDS_BYTES);

  lstm_persist<<<dim3(NWG), dim3(NTHR), LDS_BYTES, stream>>>(
      x, Wi0, Wh0, b0, Wi1, Wh1, b1, out, hring, bar);
}

// Round 10
// 3895.664 us; speedup vs baseline: 16.7068x; 1.0881x over previous
//
#include <hip/hip_runtime.h>
#include <hip/hip_bf16.h>
#include <hip/hip_fp16.h>

// 2-layer LSTM, B=32 T=512 F=1024. MFMA f16, layer-pipelined persistent kernel.
// 256 WGs x 512 thr (1 WG/CU). WGs 0-127 = L0 (t=rd), 128-255 = L1 (t=rd-1).
// R10: SPLIT-PHASE barrier — arrive() has no wait; only h-dependent waves poll
// their mailbox at round top (all-lane coalesced poll). L0 x-waves overlap the
// whole barrier resolution with next-round x loads+MFMAs. h loads: all 16
// issued up-front, vmcnt(12/8/4/0) consumption (one exposed RT).

typedef _Float16 f16x8 __attribute__((ext_vector_type(8)));
typedef __fp16 fp16x2 __attribute__((ext_vector_type(2)));
typedef float f32x4 __attribute__((ext_vector_type(4)));

#define NB 32
#define NTT 512
#define NF 1024
#define NG 4096
#define TFE (NTT * NF)
#define NWG 256
#define NTHR 512

#define W_F16X8 8192                    // [64 s][2 ntile][64 lane] f16x8
#define W_BYTES (W_F16X8 * 16)          // 131072
#define ZQSEG 33                        // 32 cols + 1 pad
#define Z_FLOATS (8 * 16 * ZQSEG)
#define LDS_BYTES (W_BYTES + Z_FLOATS * 4)   // 147968
#define RINGB 65536                     // one h phase: 32 b x 1024 f16
#define MBOX 4096                       // u32 index of mailbox region

__device__ __forceinline__ float sigm(float v) { return 1.0f / (1.0f + __expf(-v)); }
__device__ __forceinline__ float tanh_s(float v) {
  float a = fabsf(v);
  float e = __expf(-2.0f * a);
  float t = (1.0f - e) / (1.0f + e);
  return v < 0.0f ? -t : t;
}

__device__ __forceinline__ unsigned pk(float a, float b) {
  union { fp16x2 h2; unsigned u; } c;
  c.h2 = __builtin_amdgcn_cvt_pkrtz(a, b);
  return c.u;
}

__device__ __forceinline__ f16x8 cvt8(f32x4 lo, f32x4 hi) {
  union { unsigned u[4]; f16x8 h8; } u;
  u.u[0] = pk(lo[0], lo[1]);
  u.u[1] = pk(lo[2], lo[3]);
  u.u[2] = pk(hi[0], hi[1]);
  u.u[3] = pk(hi[2], hi[3]);
  return u.h8;
}

__device__ __forceinline__ unsigned ldu(const unsigned* p) {
  unsigned v;
  asm volatile("global_load_dword %0, %1, off sc0 sc1\n\ts_waitcnt vmcnt(0)"
               : "=&v"(v) : "v"(p) : "memory");
  return v;
}

// 4 coherent 16B loads from p + {0,64,128,192}; "=&v": no alias with addr %4.
__device__ __forceinline__ void ld4(f16x8 o[4], const char* p) {
  asm volatile("global_load_dwordx4 %0, %4, off sc0 sc1\n\t"
               "global_load_dwordx4 %1, %4, off offset:64 sc0 sc1\n\t"
               "global_load_dwordx4 %2, %4, off offset:128 sc0 sc1\n\t"
               "global_load_dwordx4 %3, %4, off offset:192 sc0 sc1"
               : "=&v"(o[0]), "=&v"(o[1]), "=&v"(o[2]), "=&v"(o[3])
               : "v"(p) : "memory");
}

__global__ __launch_bounds__(NTHR, 1) void lstm_persist(
    const float* __restrict__ x,
    const float* __restrict__ Wi0, const float* __restrict__ Wh0, const float* __restrict__ bv0,
    const float* __restrict__ Wi1, const float* __restrict__ Wh1, const float* __restrict__ bv1,
    float* __restrict__ out, unsigned short* __restrict__ hring_u16,
    unsigned* __restrict__ bar) {
  extern __shared__ char lds[];
  f16x8* Wl = (f16x8*)lds;                 // Wl[(s*2+ntile)*64 + lane]
  float* Zr = (float*)(lds + W_BYTES);     // Zr[(w*16+row)*33 + col]

  const int wg = blockIdx.x;
  const int tid = threadIdx.x;
  const int role = wg >> 7;        // 0: layer 0, 1: layer 1
  const int fg = wg & 127;
  const int fbase = fg * 8;
  const int w = tid >> 6;          // wave 0..7
  const int Kq = w >> 1;           // K-quarter
  const int mt = w & 1;            // M-tile
  const int lane = tid & 63;
  const int lr = lane & 15;
  const int g = lane >> 4;
  unsigned gen = 0;

  // arrival only: drain, flag store, master poll+fanout. NO trailing wait.
  auto arrive = [&]() {
    asm volatile("s_waitcnt vmcnt(0) lgkmcnt(0)" ::: "memory");
    __syncthreads();
    ++gen;
    if (tid == 0)
      asm volatile("global_store_dword %0, %1, off sc0 sc1"
                   :: "v"(&bar[wg * 16]), "v"(gen) : "memory");
    if (wg == 0) {
      if (tid < 64) {
        const unsigned* f0 = &bar[(tid * 4 + 0) * 16];
        const unsigned* f1 = &bar[(tid * 4 + 1) * 16];
        const unsigned* f2 = &bar[(tid * 4 + 2) * 16];
        const unsigned* f3 = &bar[(tid * 4 + 3) * 16];
        for (;;) {
          unsigned v0, v1, v2, v3;
          asm volatile("global_load_dword %0, %4, off sc0 sc1\n\t"
                       "global_load_dword %1, %5, off sc0 sc1\n\t"
                       "global_load_dword %2, %6, off sc0 sc1\n\t"
                       "global_load_dword %3, %7, off sc0 sc1\n\t"
                       "s_waitcnt vmcnt(0)"
                       : "=&v"(v0), "=&v"(v1), "=&v"(v2), "=&v"(v3)
                       : "v"(f0), "v"(f1), "v"(f2), "v"(f3)
                       : "memory");
          if (__all((v0 >= gen) & (v1 >= gen) & (v2 >= gen) & (v3 >= gen))) break;
        }
      }
      __syncthreads();
      if (tid < 256)
        asm volatile("global_store_dword %0, %1, off sc0 sc1"
                     :: "v"(&bar[MBOX + tid * 16]), "v"(gen) : "memory");
      __syncthreads();
    }
  };

  // wait for current gen (h-dependent waves only; all lanes poll same addr)
  auto waitgen = [&]() {
    const unsigned* mb = &bar[MBOX + wg * 16];
    for (;;) {
      if (ldu(mb) >= gen) break;
      __builtin_amdgcn_s_sleep(1);
    }
  };

  const float* Wi = role ? Wi1 : Wi0;
  const float* Wh = role ? Wh1 : Wh0;
  const float* bv = role ? bv1 : bv0;
  unsigned* h0 = (unsigned*)hring_u16;                       // layer-0 h ring
  unsigned* h1 = (unsigned*)(hring_u16 + 2 * NB * NF);       // layer-1 h ring
  unsigned* hmine = role ? h1 : h0;

  // ---- one-time W slice -> f16 LDS in B-fragment order ----
  for (int idx = tid; idx < 16384; idx += NTHR) {
    const int k = idx >> 3, chunk = idx & 7;
    const int q = chunk >> 1, half = chunk & 1;
    const float* src = (k < NF) ? (Wi + (size_t)k * NG) : (Wh + (size_t)(k - NF) * NG);
    const f32x4 v = *(const f32x4*)(src + q * NF + fbase + half * 4);
    const int s = k >> 5, kg = (k >> 3) & 3, jj = k & 7;
#pragma unroll
    for (int j = 0; j < 4; ++j) {
      const int c = q * 8 + half * 4 + j;
      _Float16* dst = (_Float16*)&Wl[((s * 2 + (c >> 4)) * 64) + kg * 16 + (c & 15)];
      dst[jj] = (_Float16)v[j];
    }
  }
  if (tid < 128) {
    const int b = tid >> 2, fp = tid & 3;
    __hip_atomic_store(&hmine[b * 512 + (fbase >> 1) + fp], 0u,
                       __ATOMIC_RELAXED, __HIP_MEMORY_SCOPE_AGENT);
  }
  float bias[4][2];
  if (tid < 128) {
    const int fp = tid & 3;
#pragma unroll
    for (int q = 0; q < 4; ++q) {
      bias[q][0] = bv[q * NF + fbase + 2 * fp];
      bias[q][1] = bv[q * NF + fbase + 2 * fp + 1];
    }
  }
  float cst[2] = {0.f, 0.f};
  __syncthreads();
  arrive();     // init barrier: full wait by everyone (W + rings ready)
  waitgen();

  for (int rd = 0; rd <= NTT; ++rd) {
    const bool doit = role == 0 ? (rd < NTT) : (rd >= 1);
    const int t = role == 0 ? rd : rd - 1;

    if (doit) {
      f32x4 acc0 = {0.f, 0.f, 0.f, 0.f}, acc1 = {0.f, 0.f, 0.f, 0.f};
      const int brow = mt * 16 + lr;

      if (role == 0 && w < 4) {
        // ---- x-part: starts immediately, overlaps barrier resolution ----
        const float* xp = x + (size_t)brow * TFE + (size_t)t * NF + Kq * 512 + g * 8;
#pragma unroll
        for (int ks = 0; ks < 16; ++ks) {
          const int s = Kq * 16 + ks;
          const f32x4 al = *(const f32x4*)(xp + ks * 32);
          const f32x4 ah = *(const f32x4*)(xp + ks * 32 + 4);
          const f16x8 A = cvt8(al, ah);
          acc0 = __builtin_amdgcn_mfma_f32_16x16x32_f16(A, Wl[(s * 2 + 0) * 64 + lane], acc0, 0, 0, 0);
          acc1 = __builtin_amdgcn_mfma_f32_16x16x32_f16(A, Wl[(s * 2 + 1) * 64 + lane], acc1, 0, 0, 0);
        }
      } else {
        // ---- h-part: wait for data, then full-issue 16-load pipeline ----
        waitgen();
        const char* hp;
        if (role == 0)
          hp = (const char*)h0 + (size_t)(rd & 1) * RINGB + brow * 2048
               + ((Kq - 2) * 512 + g * 8) * 2;
        else if (Kq < 2)
          hp = (const char*)h0 + (size_t)(rd & 1) * RINGB + brow * 2048
               + (Kq * 512 + g * 8) * 2;
        else
          hp = (const char*)h1 + (size_t)((rd + 1) & 1) * RINGB + brow * 2048
               + ((Kq - 2) * 512 + g * 8) * 2;

        f16x8 T[16];
        ld4(T + 0, hp);       ld4(T + 4, hp + 256);
        ld4(T + 8, hp + 512); ld4(T + 12, hp + 768);
        asm volatile("s_waitcnt vmcnt(12)" ::: "memory");
        __builtin_amdgcn_sched_barrier(0);
#pragma unroll
        for (int kk = 0; kk < 4; ++kk) {
          const int s = Kq * 16 + kk;
          acc0 = __builtin_amdgcn_mfma_f32_16x16x32_f16(T[kk], Wl[(s * 2 + 0) * 64 + lane], acc0, 0, 0, 0);
          acc1 = __builtin_amdgcn_mfma_f32_16x16x32_f16(T[kk], Wl[(s * 2 + 1) * 64 + lane], acc1, 0, 0, 0);
        }
        asm volatile("s_waitcnt vmcnt(8)" ::: "memory");
        __builtin_amdgcn_sched_barrier(0);
#pragma unroll
        for (int kk = 0; kk < 4; ++kk) {
          const int s = Kq * 16 + 4 + kk;
          acc0 = __builtin_amdgcn_mfma_f32_16x16x32_f16(T[4 + kk], Wl[(s * 2 + 0) * 64 + lane], acc0, 0, 0, 0);
          acc1 = __builtin_amdgcn_mfma_f32_16x16x32_f16(T[4 + kk], Wl[(s * 2 + 1) * 64 + lane], acc1, 0, 0, 0);
        }
        asm volatile("s_waitcnt vmcnt(4)" ::: "memory");
        __builtin_amdgcn_sched_barrier(0);
#pragma unroll
        for (int kk = 0; kk < 4; ++kk) {
          const int s = Kq * 16 + 8 + kk;
          acc0 = __builtin_amdgcn_mfma_f32_16x16x32_f16(T[8 + kk], Wl[(s * 2 + 0) * 64 + lane], acc0, 0, 0, 0);
          acc1 = __builtin_amdgcn_mfma_f32_16x16x32_f16(T[8 + kk], Wl[(s * 2 + 1) * 64 + lane], acc1, 0, 0, 0);
        }
        asm volatile("s_waitcnt vmcnt(0)" ::: "memory");
        __builtin_amdgcn_sched_barrier(0);
#pragma unroll
        for (int kk = 0; kk < 4; ++kk) {
          const int s = Kq * 16 + 12 + kk;
          acc0 = __builtin_amdgcn_mfma_f32_16x16x32_f16(T[12 + kk], Wl[(s * 2 + 0) * 64 + lane], acc0, 0, 0, 0);
          acc1 = __builtin_amdgcn_mfma_f32_16x16x32_f16(T[12 + kk], Wl[(s * 2 + 1) * 64 + lane], acc1, 0, 0, 0);
        }
      }

      // cross-wave K reduce: C/D layout col n=lane&15, row=(lane>>4)*4+reg
      {
        float* zb = Zr + (size_t)w * 16 * ZQSEG;
#pragma unroll
        for (int reg = 0; reg < 4; ++reg) {
          zb[(g * 4 + reg) * ZQSEG + lr] = acc0[reg];
          zb[(g * 4 + reg) * ZQSEG + 16 + lr] = acc1[reg];
        }
      }
    }
    __syncthreads();

    if (doit && tid < 128) {
      const int b = tid >> 2, fp = tid & 3;
      const int bmt = b >> 4, row = b & 15;
      float hv[2];
#pragma unroll
      for (int e = 0; e < 2; ++e) {
        const int f = 2 * fp + e;
        float zq[4];
#pragma unroll
        for (int q = 0; q < 4; ++q) {
          const int c = q * 8 + f;
          float sum = bias[q][e];
#pragma unroll
          for (int kq = 0; kq < 4; ++kq)
            sum += Zr[((kq * 2 + bmt) * 16 + row) * ZQSEG + c];
          zq[q] = sum;
        }
        const float cn = sigm(zq[1]) * cst[e] + sigm(zq[0]) * tanh_s(zq[2]);
        hv[e] = sigm(zq[3]) * tanh_s(cn);
        cst[e] = cn;
      }
      const int wph = role == 0 ? ((rd + 1) & 1) : (rd & 1);
      __hip_atomic_store(&hmine[wph * NB * 512 + b * 512 + (fbase >> 1) + fp],
                         pk(hv[0], hv[1]), __ATOMIC_RELAXED, __HIP_MEMORY_SCOPE_AGENT);
      if (role == 1)
        *(float2*)(out + (size_t)b * TFE + (size_t)t * NF + fbase + 2 * fp) =
            make_float2(hv[0], hv[1]);
    }
    arrive();   // no wait here — h-waves of next round poll their mailbox
  }
}

extern "C" void kernel_launch(void* const* d_in, const int* in_sizes, int n_in,
                              void* d_out, int out_size, void* d_ws, size_t ws_size,
                              hipStream_t stream) {
  (void)in_sizes; (void)n_in; (void)out_size; (void)ws_size;
  const float* x   = (const float*)d_in[0];
  const float* Wi0 = (const float*)d_in[1];
  const float* Wh0 = (const float*)d_in[2];
  const float* b0  = (const float*)d_in[3];
  const float* Wi1 = (const float*)d_in[4];
  const float* Wh1 = (const float*)d_in[5];
  const float* b1  = (const float*)d_in[6];
  float* out = (float*)d_out;

  unsigned short* hring = (unsigned short*)d_ws;   // h0 ring 128KB + h1 ring 128KB
  unsigned* bar = (unsigned*)((char*)d_ws + 262144);  // flags 16KB + mailboxes 16KB

  (void)hipMemsetAsync(bar, 0, 32768, stream);  // flags+mailboxes reset (replay-safe)

  (void)hipFuncSetAttribute((const void*)lstm_persist,
                            hipFuncAttributeMaxDynamicSharedMemorySize, LDS_BYTES);

  lstm_persist<<<dim3(NWG), dim3(NTHR), LDS_BYTES, stream>>>(
      x, Wi0, Wh0, b0, Wi1, Wh1, b1, out, hring, bar);
}

// Round 11
// 3877.741 us; speedup vs baseline: 16.7841x; 1.0046x over previous
//
#include <hip/hip_runtime.h>
#include <hip/hip_bf16.h>
#include <hip/hip_fp16.h>

// 2-layer LSTM, B=32 T=512 F=1024. MFMA f16, layer-pipelined persistent kernel.
// R11: DECOUPLED per-layer barriers. 256 WGs x 512 thr. WGs 0-127 = L0 (t=rd),
// WGs 128-255 = L1 (t=rd-3, lag 3). Barrier A syncs L0 only (master WG0),
// barrier B syncs L1 only (master WG128); each master polls its 128 flags and
// fans out its gen to all 256 per-WG mailboxes ([A,B] dwords, one dwordx2 poll).
// Depth-8 h rings (slot=t&7). L0 throttled by B-gen>=rd-3 (ring protection).
// L1 y0-waves need A-gen>=rd-1 (pre-satisfied: lag slack) -> only each layer's
// OWN recurrence is on its serial path; layers no longer jitter-couple.

typedef _Float16 f16x8 __attribute__((ext_vector_type(8)));
typedef __fp16 fp16x2 __attribute__((ext_vector_type(2)));
typedef float f32x4 __attribute__((ext_vector_type(4)));

#define NB 32
#define NTT 512
#define NF 1024
#define NG 4096
#define TFE (NTT * NF)
#define NWG 256
#define NTHR 512

#define W_F16X8 8192                    // [64 s][2 ntile][64 lane] f16x8
#define W_BYTES (W_F16X8 * 16)          // 131072
#define ZQSEG 33
#define Z_FLOATS (8 * 16 * ZQSEG)
#define LDS_BYTES (W_BYTES + Z_FLOATS * 4)   // 147968
#define RINGB 65536                     // one h slot: 32 b x 1024 f16
#define DEPTH 8
#define MBOX 4096                       // u32 index of mailbox region (16KB in)

__device__ __forceinline__ float sigm(float v) { return 1.0f / (1.0f + __expf(-v)); }
__device__ __forceinline__ float tanh_s(float v) {
  float a = fabsf(v);
  float e = __expf(-2.0f * a);
  float t = (1.0f - e) / (1.0f + e);
  return v < 0.0f ? -t : t;
}

__device__ __forceinline__ unsigned pk(float a, float b) {
  union { fp16x2 h2; unsigned u; } c;
  c.h2 = __builtin_amdgcn_cvt_pkrtz(a, b);
  return c.u;
}

__device__ __forceinline__ f16x8 cvt8(f32x4 lo, f32x4 hi) {
  union { unsigned u[4]; f16x8 h8; } u;
  u.u[0] = pk(lo[0], lo[1]);
  u.u[1] = pk(lo[2], lo[3]);
  u.u[2] = pk(hi[0], hi[1]);
  u.u[3] = pk(hi[2], hi[3]);
  return u.h8;
}

// 4 coherent 16B loads from p + {0,64,128,192}; "=&v": no alias with addr %4.
__device__ __forceinline__ void ld4(f16x8 o[4], const char* p) {
  asm volatile("global_load_dwordx4 %0, %4, off sc0 sc1\n\t"
               "global_load_dwordx4 %1, %4, off offset:64 sc0 sc1\n\t"
               "global_load_dwordx4 %2, %4, off offset:128 sc0 sc1\n\t"
               "global_load_dwordx4 %3, %4, off offset:192 sc0 sc1"
               : "=&v"(o[0]), "=&v"(o[1]), "=&v"(o[2]), "=&v"(o[3])
               : "v"(p) : "memory");
}

__global__ __launch_bounds__(NTHR, 1) void lstm_persist(
    const float* __restrict__ x,
    const float* __restrict__ Wi0, const float* __restrict__ Wh0, const float* __restrict__ bv0,
    const float* __restrict__ Wi1, const float* __restrict__ Wh1, const float* __restrict__ bv1,
    float* __restrict__ out, unsigned short* __restrict__ hring_u16,
    unsigned* __restrict__ bar) {
  extern __shared__ char lds[];
  f16x8* Wl = (f16x8*)lds;                 // Wl[(s*2+ntile)*64 + lane]
  float* Zr = (float*)(lds + W_BYTES);     // Zr[(w*16+row)*33 + col]

  const int wg = blockIdx.x;
  const int tid = threadIdx.x;
  const int role = wg >> 7;        // 0: layer 0, 1: layer 1
  const int fg = wg & 127;
  const int fbase = fg * 8;
  const int w = tid >> 6;          // wave 0..7
  const int Kq = w >> 1;
  const int mt = w & 1;
  const int lane = tid & 63;
  const int lr = lane & 15;
  const int g = lane >> 4;
  const bool master = (fg == 0);   // wg 0 masters A, wg 128 masters B
  unsigned gen = 0;

  // arrive to MY layer's barrier; master detects its 128 flags and fans out.
  auto arrive = [&]() {
    asm volatile("s_waitcnt vmcnt(0) lgkmcnt(0)" ::: "memory");
    __syncthreads();
    ++gen;
    if (tid == 0)
      asm volatile("global_store_dword %0, %1, off sc0 sc1"
                   :: "v"(&bar[wg * 16]), "v"(gen) : "memory");
    if (master) {
      if (tid < 64) {
        const unsigned* fa = &bar[(role * 128 + 2 * tid) * 16];
        const unsigned* fb = &bar[(role * 128 + 2 * tid + 1) * 16];
        for (;;) {
          unsigned v0, v1;
          asm volatile("global_load_dword %0, %2, off sc0 sc1\n\t"
                       "global_load_dword %1, %3, off sc0 sc1\n\t"
                       "s_waitcnt vmcnt(0)"
                       : "=&v"(v0), "=&v"(v1) : "v"(fa), "v"(fb) : "memory");
          if (__all((v0 >= gen) & (v1 >= gen))) break;
        }
      }
      __syncthreads();
      if (tid < 256)
        asm volatile("global_store_dword %0, %1, off sc0 sc1"
                     :: "v"(&bar[MBOX + tid * 16 + role]), "v"(gen) : "memory");
    }
  };

  // wait until mailbox A>=minA and B>=minB (all lanes poll same line: coalesced)
  auto waitAB = [&](unsigned minA, unsigned minB) {
    const unsigned* mb = &bar[MBOX + wg * 16];
    for (;;) {
      unsigned a, b;
      asm volatile("global_load_dwordx2 v[20:21], %2, off sc0 sc1\n\t"
                   "s_waitcnt vmcnt(0)\n\t"
                   "v_mov_b32 %0, v20\n\t"
                   "v_mov_b32 %1, v21"
                   : "=v"(a), "=v"(b) : "v"(mb) : "memory", "v20", "v21");
      if (a >= minA && b >= minB) break;
      __builtin_amdgcn_s_sleep(1);
    }
  };

  const float* Wi = role ? Wi1 : Wi0;
  const float* Wh = role ? Wh1 : Wh0;
  const float* bv = role ? bv1 : bv0;
  char* h0b = (char*)hring_u16;                        // h0 ring: DEPTH slots
  char* h1b = (char*)hring_u16 + DEPTH * RINGB;        // h1 ring
  unsigned* hmine = (unsigned*)(role ? h1b : h0b);

  // ---- one-time W slice -> f16 LDS in B-fragment order ----
  for (int idx = tid; idx < 16384; idx += NTHR) {
    const int k = idx >> 3, chunk = idx & 7;
    const int q = chunk >> 1, half = chunk & 1;
    const float* src = (k < NF) ? (Wi + (size_t)k * NG) : (Wh + (size_t)(k - NF) * NG);
    const f32x4 v = *(const f32x4*)(src + q * NF + fbase + half * 4);
    const int s = k >> 5, kg = (k >> 3) & 3, jj = k & 7;
#pragma unroll
    for (int j = 0; j < 4; ++j) {
      const int c = q * 8 + half * 4 + j;
      _Float16* dst = (_Float16*)&Wl[((s * 2 + (c >> 4)) * 64) + kg * 16 + (c & 15)];
      dst[jj] = (_Float16)v[j];
    }
  }
  // zero own ring slot 0 (h(0)=0 for L0; h1(-1)=0 for L1)
  if (tid < 128) {
    const int b = tid >> 2, fp = tid & 3;
    __hip_atomic_store(&hmine[b * 512 + (fbase >> 1) + fp], 0u,
                       __ATOMIC_RELAXED, __HIP_MEMORY_SCOPE_AGENT);
  }
  float bias[4][2];
  if (tid < 128) {
    const int fp = tid & 3;
#pragma unroll
    for (int q = 0; q < 4; ++q) {
      bias[q][0] = bv[q * NF + fbase + 2 * fp];
      bias[q][1] = bv[q * NF + fbase + 2 * fp + 1];
    }
  }
  float cst[2] = {0.f, 0.f};
  __syncthreads();
  arrive();         // gen 1: W staged + ring slot 0 zeroed
  waitAB(1, 1);

  const int nrounds = role ? (NTT + 3) : NTT;   // L1 lag 3
  for (int rd = 0; rd < nrounds; ++rd) {
    const bool doit = role == 0 ? true : (rd >= 3);
    const int t = role == 0 ? rd : rd - 3;      // timestep computed this round

    if (doit) {
      f32x4 acc0 = {0.f, 0.f, 0.f, 0.f}, acc1 = {0.f, 0.f, 0.f, 0.f};
      const int brow = mt * 16 + lr;

      if (role == 0 && w < 4) {
        // L0 x-part: no wait, overlaps all sync latency
        const float* xp = x + (size_t)brow * TFE + (size_t)t * NF + Kq * 512 + g * 8;
#pragma unroll
        for (int ks = 0; ks < 16; ++ks) {
          const int s = Kq * 16 + ks;
          const f32x4 al = *(const f32x4*)(xp + ks * 32);
          const f32x4 ah = *(const f32x4*)(xp + ks * 32 + 4);
          const f16x8 A = cvt8(al, ah);
          acc0 = __builtin_amdgcn_mfma_f32_16x16x32_f16(A, Wl[(s * 2 + 0) * 64 + lane], acc0, 0, 0, 0);
          acc1 = __builtin_amdgcn_mfma_f32_16x16x32_f16(A, Wl[(s * 2 + 1) * 64 + lane], acc1, 0, 0, 0);
        }
      } else {
        // waits: L0 h: A>=rd+1 (serial) + throttle B>=rd-3.
        // L1 y0: A>=rd-1 (pre-satisfied). L1 h1: B>=rd+1 (serial; rd==3 -> init).
        unsigned minA = 0, minB = 0;
        const char* hp;
        if (role == 0) {
          minA = rd + 1;
          minB = (rd >= 4) ? (unsigned)(rd - 3) : 0u;
          hp = h0b + (size_t)(rd & 7) * RINGB + brow * 2048
               + ((Kq - 2) * 512 + g * 8) * 2;
        } else if (Kq < 2) {
          minA = rd - 1;
          hp = h0b + (size_t)((rd - 2) & 7) * RINGB + brow * 2048
               + (Kq * 512 + g * 8) * 2;            // y0(t)=h0(t+1)=h0(rd-2)
        } else {
          minB = (rd == 3) ? 1u : (unsigned)(rd + 1);
          hp = h1b + (size_t)((rd - 3) & 7) * RINGB + brow * 2048
               + ((Kq - 2) * 512 + g * 8) * 2;      // h1(t-1), slot (t)&7
        }
        waitAB(minA, minB);

        f16x8 T[16];
        ld4(T + 0, hp);       ld4(T + 4, hp + 256);
        ld4(T + 8, hp + 512); ld4(T + 12, hp + 768);
        asm volatile("s_waitcnt vmcnt(12)" ::: "memory");
        __builtin_amdgcn_sched_barrier(0);
#pragma unroll
        for (int kk = 0; kk < 4; ++kk) {
          const int s = Kq * 16 + kk;
          acc0 = __builtin_amdgcn_mfma_f32_16x16x32_f16(T[kk], Wl[(s * 2 + 0) * 64 + lane], acc0, 0, 0, 0);
          acc1 = __builtin_amdgcn_mfma_f32_16x16x32_f16(T[kk], Wl[(s * 2 + 1) * 64 + lane], acc1, 0, 0, 0);
        }
        asm volatile("s_waitcnt vmcnt(8)" ::: "memory");
        __builtin_amdgcn_sched_barrier(0);
#pragma unroll
        for (int kk = 0; kk < 4; ++kk) {
          const int s = Kq * 16 + 4 + kk;
          acc0 = __builtin_amdgcn_mfma_f32_16x16x32_f16(T[4 + kk], Wl[(s * 2 + 0) * 64 + lane], acc0, 0, 0, 0);
          acc1 = __builtin_amdgcn_mfma_f32_16x16x32_f16(T[4 + kk], Wl[(s * 2 + 1) * 64 + lane], acc1, 0, 0, 0);
        }
        asm volatile("s_waitcnt vmcnt(4)" ::: "memory");
        __builtin_amdgcn_sched_barrier(0);
#pragma unroll
        for (int kk = 0; kk < 4; ++kk) {
          const int s = Kq * 16 + 8 + kk;
          acc0 = __builtin_amdgcn_mfma_f32_16x16x32_f16(T[8 + kk], Wl[(s * 2 + 0) * 64 + lane], acc0, 0, 0, 0);
          acc1 = __builtin_amdgcn_mfma_f32_16x16x32_f16(T[8 + kk], Wl[(s * 2 + 1) * 64 + lane], acc1, 0, 0, 0);
        }
        asm volatile("s_waitcnt vmcnt(0)" ::: "memory");
        __builtin_amdgcn_sched_barrier(0);
#pragma unroll
        for (int kk = 0; kk < 4; ++kk) {
          const int s = Kq * 16 + 12 + kk;
          acc0 = __builtin_amdgcn_mfma_f32_16x16x32_f16(T[12 + kk], Wl[(s * 2 + 0) * 64 + lane], acc0, 0, 0, 0);
          acc1 = __builtin_amdgcn_mfma_f32_16x16x32_f16(T[12 + kk], Wl[(s * 2 + 1) * 64 + lane], acc1, 0, 0, 0);
        }
      }

      // cross-wave K reduce
      {
        float* zb = Zr + (size_t)w * 16 * ZQSEG;
#pragma unroll
        for (int reg = 0; reg < 4; ++reg) {
          zb[(g * 4 + reg) * ZQSEG + lr] = acc0[reg];
          zb[(g * 4 + reg) * ZQSEG + 16 + lr] = acc1[reg];
        }
      }
    }
    __syncthreads();

    if (doit && tid < 128) {
      const int b = tid >> 2, fp = tid & 3;
      const int bmt = b >> 4, row = b & 15;
      float hv[2];
#pragma unroll
      for (int e = 0; e < 2; ++e) {
        const int f = 2 * fp + e;
        float zq[4];
#pragma unroll
        for (int q = 0; q < 4; ++q) {
          const int c = q * 8 + f;
          float sum = bias[q][e];
#pragma unroll
          for (int kq = 0; kq < 4; ++kq)
            sum += Zr[((kq * 2 + bmt) * 16 + row) * ZQSEG + c];
          zq[q] = sum;
        }
        const float cn = sigm(zq[1]) * cst[e] + sigm(zq[0]) * tanh_s(zq[2]);
        hv[e] = sigm(zq[3]) * tanh_s(cn);
        cst[e] = cn;
      }
      // store h(t+1) into slot (t+1)&7 of my ring
      const int wslot = (t + 1) & 7;
      __hip_atomic_store(&hmine[(size_t)wslot * (RINGB / 4) + b * 512 + (fbase >> 1) + fp],
                         pk(hv[0], hv[1]), __ATOMIC_RELAXED, __HIP_MEMORY_SCOPE_AGENT);
      if (role == 1)
        *(float2*)(out + (size_t)b * TFE + (size_t)t * NF + fbase + 2 * fp) =
            make_float2(hv[0], hv[1]);
    }
    arrive();   // my layer's barrier only
  }
}

extern "C" void kernel_launch(void* const* d_in, const int* in_sizes, int n_in,
                              void* d_out, int out_size, void* d_ws, size_t ws_size,
                              hipStream_t stream) {
  (void)in_sizes; (void)n_in; (void)out_size; (void)ws_size;
  const float* x   = (const float*)d_in[0];
  const float* Wi0 = (const float*)d_in[1];
  const float* Wh0 = (const float*)d_in[2];
  const float* b0  = (const float*)d_in[3];
  const float* Wi1 = (const float*)d_in[4];
  const float* Wh1 = (const float*)d_in[5];
  const float* b1  = (const float*)d_in[6];
  float* out = (float*)d_out;

  unsigned short* hring = (unsigned short*)d_ws;       // h0[8]+h1[8] slots, 1MB
  unsigned* bar = (unsigned*)((char*)d_ws + 2 * DEPTH * RINGB);  // flags+mbox 32KB

  (void)hipMemsetAsync(bar, 0, 32768, stream);  // replay-safe barrier reset

  (void)hipFuncSetAttribute((const void*)lstm_persist,
                            hipFuncAttributeMaxDynamicSharedMemorySize, LDS_BYTES);

  lstm_persist<<<dim3(NWG), dim3(NTHR), LDS_BYTES, stream>>>(
      x, Wi0, Wh0, b0, Wi1, Wh1, b1, out, hring, bar);
}

// Round 12
// 3782.140 us; speedup vs baseline: 17.2083x; 1.0253x over previous
//
#include <hip/hip_runtime.h>
#include <hip/hip_bf16.h>
#include <hip/hip_fp16.h>

// 2-layer LSTM, B=32 T=512 F=1024. MFMA f16, layer-pipelined persistent kernel.
// R12 = R11 (decoupled per-layer barriers, depth-8 rings, lag-3) plus:
//  - in-asm poll loops (consumer mbox + master detect): no C overhead, no s_sleep
//  - fast transcendental gates: v_exp_f32 (exp2) + v_rcp_f32, branch-free tanh

typedef _Float16 f16x8 __attribute__((ext_vector_type(8)));
typedef __fp16 fp16x2 __attribute__((ext_vector_type(2)));
typedef float f32x4 __attribute__((ext_vector_type(4)));

#define NB 32
#define NTT 512
#define NF 1024
#define NG 4096
#define TFE (NTT * NF)
#define NWG 256
#define NTHR 512

#define W_F16X8 8192                    // [64 s][2 ntile][64 lane] f16x8
#define W_BYTES (W_F16X8 * 16)          // 131072
#define ZQSEG 33
#define Z_FLOATS (8 * 16 * ZQSEG)
#define LDS_BYTES (W_BYTES + Z_FLOATS * 4)   // 147968
#define RINGB 65536                     // one h slot: 32 b x 1024 f16
#define DEPTH 8
#define MBOX 4096                       // u32 index of mailbox region (16KB in)

#define LOG2E 1.44269504f

// fast sigmoid / tanh on the trans pipe (v_exp_f32 is 2^x; v_rcp_f32 approx).
__device__ __forceinline__ float sigm(float v) {
  return __builtin_amdgcn_rcpf(1.0f + __builtin_amdgcn_exp2f(-LOG2E * v));
}
__device__ __forceinline__ float tanh_s(float v) {
  // tanh(v) = 2*sigm(2v) - 1  (branch-free, inf-safe: rcp(inf)=0 -> -1)
  return 2.0f * __builtin_amdgcn_rcpf(1.0f + __builtin_amdgcn_exp2f(-2.0f * LOG2E * v)) - 1.0f;
}

__device__ __forceinline__ unsigned pk(float a, float b) {
  union { fp16x2 h2; unsigned u; } c;
  c.h2 = __builtin_amdgcn_cvt_pkrtz(a, b);
  return c.u;
}

__device__ __forceinline__ f16x8 cvt8(f32x4 lo, f32x4 hi) {
  union { unsigned u[4]; f16x8 h8; } u;
  u.u[0] = pk(lo[0], lo[1]);
  u.u[1] = pk(lo[2], lo[3]);
  u.u[2] = pk(hi[0], hi[1]);
  u.u[3] = pk(hi[2], hi[3]);
  return u.h8;
}

// 4 coherent 16B loads from p + {0,64,128,192}; "=&v": no alias with addr %4.
__device__ __forceinline__ void ld4(f16x8 o[4], const char* p) {
  asm volatile("global_load_dwordx4 %0, %4, off sc0 sc1\n\t"
               "global_load_dwordx4 %1, %4, off offset:64 sc0 sc1\n\t"
               "global_load_dwordx4 %2, %4, off offset:128 sc0 sc1\n\t"
               "global_load_dwordx4 %3, %4, off offset:192 sc0 sc1"
               : "=&v"(o[0]), "=&v"(o[1]), "=&v"(o[2]), "=&v"(o[3])
               : "v"(p) : "memory");
}

__global__ __launch_bounds__(NTHR, 1) void lstm_persist(
    const float* __restrict__ x,
    const float* __restrict__ Wi0, const float* __restrict__ Wh0, const float* __restrict__ bv0,
    const float* __restrict__ Wi1, const float* __restrict__ Wh1, const float* __restrict__ bv1,
    float* __restrict__ out, unsigned short* __restrict__ hring_u16,
    unsigned* __restrict__ bar) {
  extern __shared__ char lds[];
  f16x8* Wl = (f16x8*)lds;                 // Wl[(s*2+ntile)*64 + lane]
  float* Zr = (float*)(lds + W_BYTES);     // Zr[(w*16+row)*33 + col]

  const int wg = blockIdx.x;
  const int tid = threadIdx.x;
  const int role = wg >> 7;        // 0: layer 0, 1: layer 1
  const int fg = wg & 127;
  const int fbase = fg * 8;
  const int w = tid >> 6;          // wave 0..7
  const int Kq = w >> 1;
  const int mt = w & 1;
  const int lane = tid & 63;
  const int lr = lane & 15;
  const int g = lane >> 4;
  const bool master = (fg == 0);   // wg 0 masters A, wg 128 masters B
  unsigned gen = 0;

  // arrive to MY layer's barrier; master detects its 128 flags (in-asm poll)
  // and fans its gen out to all 256 mailboxes.
  auto arrive = [&]() {
    asm volatile("s_waitcnt vmcnt(0) lgkmcnt(0)" ::: "memory");
    __syncthreads();
    ++gen;
    if (tid == 0)
      asm volatile("global_store_dword %0, %1, off sc0 sc1"
                   :: "v"(&bar[wg * 16]), "v"(gen) : "memory");
    if (master) {
      if (tid < 64) {
        const unsigned* fa = &bar[(role * 128 + 2 * tid) * 16];
        const unsigned* fb = &bar[(role * 128 + 2 * tid + 1) * 16];
        // loop while ANY lane sees (fa < gen) || (fb < gen)
        asm volatile("L%=:\n\t"
                     "global_load_dword v20, %0, off sc0 sc1\n\t"
                     "global_load_dword v21, %1, off sc0 sc1\n\t"
                     "s_waitcnt vmcnt(0)\n\t"
                     "v_cmp_lt_u32 vcc, v20, %2\n\t"
                     "s_mov_b64 s[14:15], vcc\n\t"
                     "v_cmp_lt_u32 vcc, v21, %2\n\t"
                     "s_or_b64 vcc, vcc, s[14:15]\n\t"
                     "s_cbranch_vccnz L%="
                     :: "v"(fa), "v"(fb), "v"(gen)
                     : "memory", "v20", "v21", "vcc", "s14", "s15");
      }
      __syncthreads();
      if (tid < 256)
        asm volatile("global_store_dword %0, %1, off sc0 sc1"
                     :: "v"(&bar[MBOX + tid * 16 + role]), "v"(gen) : "memory");
    }
  };

  // wait until mailbox A>=minA and B>=minB (all lanes same line; in-asm loop)
  auto waitAB = [&](unsigned minA, unsigned minB) {
    const unsigned* mb = &bar[MBOX + wg * 16];
    asm volatile("L%=:\n\t"
                 "global_load_dwordx2 v[20:21], %0, off sc0 sc1\n\t"
                 "s_waitcnt vmcnt(0)\n\t"
                 "v_cmp_lt_u32 vcc, v20, %1\n\t"
                 "s_mov_b64 s[14:15], vcc\n\t"
                 "v_cmp_lt_u32 vcc, v21, %2\n\t"
                 "s_or_b64 vcc, vcc, s[14:15]\n\t"
                 "s_cbranch_vccnz L%="
                 :: "v"(mb), "v"(minA), "v"(minB)
                 : "memory", "v20", "v21", "vcc", "s14", "s15");
  };

  const float* Wi = role ? Wi1 : Wi0;
  const float* Wh = role ? Wh1 : Wh0;
  const float* bv = role ? bv1 : bv0;
  char* h0b = (char*)hring_u16;                        // h0 ring: DEPTH slots
  char* h1b = (char*)hring_u16 + DEPTH * RINGB;        // h1 ring
  unsigned* hmine = (unsigned*)(role ? h1b : h0b);

  // ---- one-time W slice -> f16 LDS in B-fragment order ----
  for (int idx = tid; idx < 16384; idx += NTHR) {
    const int k = idx >> 3, chunk = idx & 7;
    const int q = chunk >> 1, half = chunk & 1;
    const float* src = (k < NF) ? (Wi + (size_t)k * NG) : (Wh + (size_t)(k - NF) * NG);
    const f32x4 v = *(const f32x4*)(src + q * NF + fbase + half * 4);
    const int s = k >> 5, kg = (k >> 3) & 3, jj = k & 7;
#pragma unroll
    for (int j = 0; j < 4; ++j) {
      const int c = q * 8 + half * 4 + j;
      _Float16* dst = (_Float16*)&Wl[((s * 2 + (c >> 4)) * 64) + kg * 16 + (c & 15)];
      dst[jj] = (_Float16)v[j];
    }
  }
  // zero own ring slot 0 (h(0)=0 for L0; h1(-1)=0 for L1)
  if (tid < 128) {
    const int b = tid >> 2, fp = tid & 3;
    __hip_atomic_store(&hmine[b * 512 + (fbase >> 1) + fp], 0u,
                       __ATOMIC_RELAXED, __HIP_MEMORY_SCOPE_AGENT);
  }
  float bias[4][2];
  if (tid < 128) {
    const int fp = tid & 3;
#pragma unroll
    for (int q = 0; q < 4; ++q) {
      bias[q][0] = bv[q * NF + fbase + 2 * fp];
      bias[q][1] = bv[q * NF + fbase + 2 * fp + 1];
    }
  }
  float cst[2] = {0.f, 0.f};
  __syncthreads();
  arrive();         // gen 1: W staged + ring slot 0 zeroed
  waitAB(1, 1);

  const int nrounds = role ? (NTT + 3) : NTT;   // L1 lag 3
  for (int rd = 0; rd < nrounds; ++rd) {
    const bool doit = role == 0 ? true : (rd >= 3);
    const int t = role == 0 ? rd : rd - 3;      // timestep computed this round

    if (doit) {
      f32x4 acc0 = {0.f, 0.f, 0.f, 0.f}, acc1 = {0.f, 0.f, 0.f, 0.f};
      const int brow = mt * 16 + lr;

      if (role == 0 && w < 4) {
        // L0 x-part: no wait, overlaps all sync latency
        const float* xp = x + (size_t)brow * TFE + (size_t)t * NF + Kq * 512 + g * 8;
#pragma unroll
        for (int ks = 0; ks < 16; ++ks) {
          const int s = Kq * 16 + ks;
          const f32x4 al = *(const f32x4*)(xp + ks * 32);
          const f32x4 ah = *(const f32x4*)(xp + ks * 32 + 4);
          const f16x8 A = cvt8(al, ah);
          acc0 = __builtin_amdgcn_mfma_f32_16x16x32_f16(A, Wl[(s * 2 + 0) * 64 + lane], acc0, 0, 0, 0);
          acc1 = __builtin_amdgcn_mfma_f32_16x16x32_f16(A, Wl[(s * 2 + 1) * 64 + lane], acc1, 0, 0, 0);
        }
      } else {
        // waits: L0 h: A>=rd+1 (serial) + throttle B>=rd-3.
        // L1 y0: A>=rd-1 (pre-satisfied). L1 h1: B>=rd+1 (serial; rd==3 -> init).
        unsigned minA = 0, minB = 0;
        const char* hp;
        if (role == 0) {
          minA = rd + 1;
          minB = (rd >= 4) ? (unsigned)(rd - 3) : 0u;
          hp = h0b + (size_t)(rd & 7) * RINGB + brow * 2048
               + ((Kq - 2) * 512 + g * 8) * 2;
        } else if (Kq < 2) {
          minA = rd - 1;
          hp = h0b + (size_t)((rd - 2) & 7) * RINGB + brow * 2048
               + (Kq * 512 + g * 8) * 2;            // y0(t)=h0(t+1)=h0(rd-2)
        } else {
          minB = (rd == 3) ? 1u : (unsigned)(rd + 1);
          hp = h1b + (size_t)((rd - 3) & 7) * RINGB + brow * 2048
               + ((Kq - 2) * 512 + g * 8) * 2;      // h1(t-1), slot (t)&7
        }
        waitAB(minA, minB);

        f16x8 T[16];
        ld4(T + 0, hp);       ld4(T + 4, hp + 256);
        ld4(T + 8, hp + 512); ld4(T + 12, hp + 768);
        asm volatile("s_waitcnt vmcnt(12)" ::: "memory");
        __builtin_amdgcn_sched_barrier(0);
#pragma unroll
        for (int kk = 0; kk < 4; ++kk) {
          const int s = Kq * 16 + kk;
          acc0 = __builtin_amdgcn_mfma_f32_16x16x32_f16(T[kk], Wl[(s * 2 + 0) * 64 + lane], acc0, 0, 0, 0);
          acc1 = __builtin_amdgcn_mfma_f32_16x16x32_f16(T[kk], Wl[(s * 2 + 1) * 64 + lane], acc1, 0, 0, 0);
        }
        asm volatile("s_waitcnt vmcnt(8)" ::: "memory");
        __builtin_amdgcn_sched_barrier(0);
#pragma unroll
        for (int kk = 0; kk < 4; ++kk) {
          const int s = Kq * 16 + 4 + kk;
          acc0 = __builtin_amdgcn_mfma_f32_16x16x32_f16(T[4 + kk], Wl[(s * 2 + 0) * 64 + lane], acc0, 0, 0, 0);
          acc1 = __builtin_amdgcn_mfma_f32_16x16x32_f16(T[4 + kk], Wl[(s * 2 + 1) * 64 + lane], acc1, 0, 0, 0);
        }
        asm volatile("s_waitcnt vmcnt(4)" ::: "memory");
        __builtin_amdgcn_sched_barrier(0);
#pragma unroll
        for (int kk = 0; kk < 4; ++kk) {
          const int s = Kq * 16 + 8 + kk;
          acc0 = __builtin_amdgcn_mfma_f32_16x16x32_f16(T[8 + kk], Wl[(s * 2 + 0) * 64 + lane], acc0, 0, 0, 0);
          acc1 = __builtin_amdgcn_mfma_f32_16x16x32_f16(T[8 + kk], Wl[(s * 2 + 1) * 64 + lane], acc1, 0, 0, 0);
        }
        asm volatile("s_waitcnt vmcnt(0)" ::: "memory");
        __builtin_amdgcn_sched_barrier(0);
#pragma unroll
        for (int kk = 0; kk < 4; ++kk) {
          const int s = Kq * 16 + 12 + kk;
          acc0 = __builtin_amdgcn_mfma_f32_16x16x32_f16(T[12 + kk], Wl[(s * 2 + 0) * 64 + lane], acc0, 0, 0, 0);
          acc1 = __builtin_amdgcn_mfma_f32_16x16x32_f16(T[12 + kk], Wl[(s * 2 + 1) * 64 + lane], acc1, 0, 0, 0);
        }
      }

      // cross-wave K reduce
      {
        float* zb = Zr + (size_t)w * 16 * ZQSEG;
#pragma unroll
        for (int reg = 0; reg < 4; ++reg) {
          zb[(g * 4 + reg) * ZQSEG + lr] = acc0[reg];
          zb[(g * 4 + reg) * ZQSEG + 16 + lr] = acc1[reg];
        }
      }
    }
    __syncthreads();

    if (doit && tid < 128) {
      const int b = tid >> 2, fp = tid & 3;
      const int bmt = b >> 4, row = b & 15;
      float hv[2];
#pragma unroll
      for (int e = 0; e < 2; ++e) {
        const int f = 2 * fp + e;
        float zq[4];
#pragma unroll
        for (int q = 0; q < 4; ++q) {
          const int c = q * 8 + f;
          float sum = bias[q][e];
#pragma unroll
          for (int kq = 0; kq < 4; ++kq)
            sum += Zr[((kq * 2 + bmt) * 16 + row) * ZQSEG + c];
          zq[q] = sum;
        }
        const float cn = sigm(zq[1]) * cst[e] + sigm(zq[0]) * tanh_s(zq[2]);
        hv[e] = sigm(zq[3]) * tanh_s(cn);
        cst[e] = cn;
      }
      // store h(t+1) into slot (t+1)&7 of my ring
      const int wslot = (t + 1) & 7;
      __hip_atomic_store(&hmine[(size_t)wslot * (RINGB / 4) + b * 512 + (fbase >> 1) + fp],
                         pk(hv[0], hv[1]), __ATOMIC_RELAXED, __HIP_MEMORY_SCOPE_AGENT);
      if (role == 1)
        *(float2*)(out + (size_t)b * TFE + (size_t)t * NF + fbase + 2 * fp) =
            make_float2(hv[0], hv[1]);
    }
    arrive();   // my layer's barrier only
  }
}

extern "C" void kernel_launch(void* const* d_in, const int* in_sizes, int n_in,
                              void* d_out, int out_size, void* d_ws, size_t ws_size,
                              hipStream_t stream) {
  (void)in_sizes; (void)n_in; (void)out_size; (void)ws_size;
  const float* x   = (const float*)d_in[0];
  const float* Wi0 = (const float*)d_in[1];
  const float* Wh0 = (const float*)d_in[2];
  const float* b0  = (const float*)d_in[3];
  const float* Wi1 = (const float*)d_in[4];
  const float* Wh1 = (const float*)d_in[5];
  const float* b1  = (const float*)d_in[6];
  float* out = (float*)d_out;

  unsigned short* hring = (unsigned short*)d_ws;       // h0[8]+h1[8] slots, 1MB
  unsigned* bar = (unsigned*)((char*)d_ws + 2 * DEPTH * RINGB);  // flags+mbox 32KB

  (void)hipMemsetAsync(bar, 0, 32768, stream);  // replay-safe barrier reset

  (void)hipFuncSetAttribute((const void*)lstm_persist,
                            hipFuncAttributeMaxDynamicSharedMemorySize, LDS_BYTES);

  lstm_persist<<<dim3(NWG), dim3(NTHR), LDS_BYTES, stream>>>(
      x, Wi0, Wh0, b0, Wi1, Wh1, b1, out, hring, bar);
}